// Round 1
// baseline (497.765 us; speedup 1.0000x reference)
//
#include <hip/hip_runtime.h>
#include <math.h>

// ---------------- problem constants ----------------
#define BB    8
#define NLEN  8192          // sequence length (FFT size)
#define CC    512           // channels
#define HH    8             // heads
#define DH    64            // head dim
#define MH    4096          // NLEN/2 (complex FFT size)
#define FREQ  4097          // NLEN/2+1 rfft bins
#define FP    4104          // padded spectrum row length (float2 units)
#define NSEQ  (BB*CC)       // 4096 rows

// scratch: two regions of NSEQ*FP float2
#define REGION_BYTES ((size_t)NSEQ * FP * 8ull)

static __device__ __align__(256) unsigned char g_scratch[2ull * (size_t)NSEQ * FP * 8ull];

// ---------------- complex helpers ----------------
__device__ __forceinline__ float2 cadd(float2 a, float2 b){ return make_float2(a.x+b.x, a.y+b.y); }
__device__ __forceinline__ float2 csub(float2 a, float2 b){ return make_float2(a.x-b.x, a.y-b.y); }
__device__ __forceinline__ float2 cmul(float2 a, float2 b){
  return make_float2(fmaf(a.x, b.x, -(a.y*b.y)), fmaf(a.x, b.y, a.y*b.x));
}

__device__ __forceinline__ float gelu_exact(float v){
  return 0.5f * v * (1.0f + erff(v * 0.70710678118654752440f));
}

// ---------------- tiled transpose: per batch slice [R][Cc] -> [Cc][R] ----------------
__global__ __launch_bounds__(256) void transpose_k(const float* __restrict__ in,
                                                   float* __restrict__ out,
                                                   int R, int Cc){
  __shared__ float tile[32][33];
  int b  = blockIdx.z;
  const float* src = in  + (size_t)b * R * Cc;
  float*       dst = out + (size_t)b * R * Cc;
  int c0 = blockIdx.x * 32;
  int r0 = blockIdx.y * 32;
  int tx = threadIdx.x, ty = threadIdx.y;
  #pragma unroll
  for (int k = 0; k < 32; k += 8)
    tile[ty + k][tx] = src[(size_t)(r0 + ty + k) * Cc + c0 + tx];
  __syncthreads();
  #pragma unroll
  for (int k = 0; k < 32; k += 8)
    dst[(size_t)(c0 + ty + k) * R + r0 + tx] = tile[tx][ty + k];
}

// ---------------- Stockham radix-4 pass (Govindaraju-style) ----------------
// SIGN=-1 forward DFT, SIGN=+1 unnormalized inverse DFT. N=4096, 256 threads, 4 butterflies/thread.
template<int SIGN>
__device__ __forceinline__ void fft_pass(const float2* __restrict__ a,
                                         float2* __restrict__ b,
                                         int Ns, int t){
  #pragma unroll
  for (int q = 0; q < 4; ++q){
    int j = t + 256*q;
    float2 v0 = a[j];
    float2 v1 = a[j + 1024];
    float2 v2 = a[j + 2048];
    float2 v3 = a[j + 3072];
    int jm = j & (Ns - 1);
    float ang = (float)SIGN * 6.2831853071795864769f * (float)jm / (float)(4*Ns);
    float sn, cs; __sincosf(ang, &sn, &cs);
    float2 w1 = make_float2(cs, sn);
    float2 w2 = cmul(w1, w1);
    float2 w3 = cmul(w2, w1);
    v1 = cmul(v1, w1);
    v2 = cmul(v2, w2);
    v3 = cmul(v3, w3);
    float2 s02 = cadd(v0, v2), d02 = csub(v0, v2);
    float2 s13 = cadd(v1, v3), d13 = csub(v1, v3);
    float2 X0 = cadd(s02, s13);
    float2 X2 = csub(s02, s13);
    // X1 = d02 + SIGN*i*d13 ; X3 = d02 - SIGN*i*d13 ; i*d13 = (-d13.y, d13.x)
    float2 id = make_float2(-(float)SIGN * d13.y, (float)SIGN * d13.x);
    float2 X1 = cadd(d02, id);
    float2 X3 = csub(d02, id);
    int idxD = ((j - jm) << 2) + jm;
    b[idxD         ] = X0;
    b[idxD +     Ns] = X1;
    b[idxD + 2*Ns  ] = X2;
    b[idxD + 3*Ns  ] = X3;
  }
}

#define ORTHO_S 0.011048543456039806f   // 1/sqrt(8192)

// ---------------- forward rfft-8192 of one contiguous row ----------------
__global__ __launch_bounds__(256) void fft_fwd_k(const float* __restrict__ xt,
                                                 float2* __restrict__ spec){
  __shared__ float2 bufA[MH];
  __shared__ float2 bufB[MH];
  int t = threadIdx.x;
  size_t row = blockIdx.x;
  const float2* src = (const float2*)(xt + row * (size_t)NLEN);
  #pragma unroll
  for (int q = 0; q < 16; ++q) bufA[t + 256*q] = src[t + 256*q];  // z[m]=x[2m]+i x[2m+1]
  __syncthreads();
  float2 *pa = bufA, *pb = bufB;
  #pragma unroll
  for (int p = 0; p < 6; ++p){
    int Ns = 1 << (2*p);
    fft_pass<-1>(pa, pb, Ns, t);
    __syncthreads();
    float2* tmp = pa; pa = pb; pb = tmp;
  }
  // unpack packed-complex FFT into rfft bins, ortho scale
  float2* dst = spec + row * (size_t)FP;
  #pragma unroll
  for (int q = 0; q < 16; ++q){
    int k = t + 256*q;                       // 0..4095
    float2 zk = pa[k];
    float2 zc = pa[(MH - k) & (MH - 1)];
    float ex = 0.5f*(zk.x + zc.x);
    float ey = 0.5f*(zk.y - zc.y);
    float ux = zk.x - zc.x;
    float uy = zk.y + zc.y;
    float ox =  0.5f*uy;                     // O = -0.5i*(zk - conj(zc))
    float oy = -0.5f*ux;
    float ang = -6.2831853071795864769f * (float)k / (float)NLEN;
    float sn, cs; __sincosf(ang, &sn, &cs);
    float xr = ex + cs*ox - sn*oy;
    float xi = ey + cs*oy + sn*ox;
    dst[k] = make_float2(ORTHO_S*xr, ORTHO_S*xi);
  }
  if (t == 0){
    float2 z0 = pa[0];
    dst[MH] = make_float2(ORTHO_S*(z0.x - z0.y), 0.0f);   // Nyquist bin (real)
  }
}

// ---------------- inverse rfft-8192 -> one contiguous row ----------------
__global__ __launch_bounds__(256) void fft_inv_k(const float2* __restrict__ spec,
                                                 float* __restrict__ yt){
  __shared__ float2 bufA[MH];
  __shared__ float2 bufB[MH];
  int t = threadIdx.x;
  size_t row = blockIdx.x;
  const float2* src = spec + row * (size_t)FP;
  #pragma unroll
  for (int q = 0; q < 16; ++q){
    int k = t + 256*q;                       // 0..4095
    float2 xk = src[k];
    float2 xc = src[MH - k];                 // k=0 -> bin 4096
    if (k == 0){ xk.y = 0.0f; xc.y = 0.0f; } // pocketfft c2r drops imag at DC/Nyquist
    float ex = xk.x + xc.x;                  // E' = X[k] + conj(X[M-k])
    float ey = xk.y - xc.y;
    float dx = xk.x - xc.x;
    float dy = xk.y + xc.y;
    float ang = 6.2831853071795864769f * (float)k / (float)NLEN;
    float sn, cs; __sincosf(ang, &sn, &cs);
    float ox = cs*dx - sn*dy;                // O' = (X[k]-conj(X[M-k])) * e^{+2pi i k/N}
    float oy = cs*dy + sn*dx;
    bufA[k] = make_float2(ex - oy, ey + ox); // Z = E' + i O'
  }
  __syncthreads();
  float2 *pa = bufA, *pb = bufB;
  #pragma unroll
  for (int p = 0; p < 6; ++p){
    int Ns = 1 << (2*p);
    fft_pass<1>(pa, pb, Ns, t);
    __syncthreads();
    float2* tmp = pa; pa = pb; pb = tmp;
  }
  float2* dst = (float2*)(yt + row * (size_t)NLEN);
  #pragma unroll
  for (int q = 0; q < 16; ++q){
    int m = t + 256*q;
    float2 w = pa[m];
    dst[m] = make_float2(ORTHO_S*w.x, ORTHO_S*w.y);  // y[2m], y[2m+1]
  }
}

// ---------------- middle: per-(b,h,f-tile) two-stage complex MLP ----------------
__global__ __launch_bounds__(256) void afno_mid_k(const float2* __restrict__ spec_in,
                                                  float2* __restrict__ spec_out,
                                                  const float* __restrict__ w1,
                                                  const float* __restrict__ b1,
                                                  const float* __restrict__ w2,
                                                  const float* __restrict__ b2){
  __shared__ float2 sX[64][34];   // [i][f_local]
  __shared__ float2 sO[64][34];   // [i2][f_local] (stage-1 output)
  __shared__ float2 sW[64][65];   // [i][o] = (w_r, w_i)
  int t  = threadIdx.x;
  int bx = blockIdx.x;            // f tile (32 bins)
  int h  = blockIdx.y;
  int b  = blockIdx.z;
  int F0 = bx * 32;
  size_t rowbase = ((size_t)b * HH + h) * DH;   // global spectrum row = rowbase + i

  // load X tile
  {
    int fl = t & 31;
    int i0 = t >> 5;
    int fglob = F0 + fl;
    bool ok = fglob < FREQ;
    #pragma unroll
    for (int ii = 0; ii < 8; ++ii){
      int i = i0 + 8*ii;
      float2 v = ok ? spec_in[(rowbase + i) * (size_t)FP + fglob] : make_float2(0.f, 0.f);
      sX[i][fl] = v;
    }
  }
  // load W1 (real & imag planes packed)
  {
    const float* w1r = w1 +           (size_t)h * (DH*DH);
    const float* w1i = w1 + 32768ull + (size_t)h * (DH*DH);
    #pragma unroll
    for (int u = 0; u < 16; ++u){
      int idx = t + 256*u;
      int i = idx >> 6, o = idx & 63;
      sW[i][o] = make_float2(w1r[idx], w1i[idx]);
    }
  }
  __syncthreads();

  int fgrp = t & 15, ogrp = t >> 4;
  int fl0 = fgrp * 2;
  int ob  = ogrp * 4;

  float ar[2][4], ai[2][4];
  #pragma unroll
  for (int a = 0; a < 2; ++a)
    #pragma unroll
    for (int o = 0; o < 4; ++o){ ar[a][o] = 0.f; ai[a][o] = 0.f; }

  // stage 1: o1 = gelu(X (complex*) W1 + b1)
  #pragma unroll 4
  for (int i = 0; i < 64; ++i){
    float2 x0 = sX[i][fl0];
    float2 x1 = sX[i][fl0 + 1];
    #pragma unroll
    for (int o = 0; o < 4; ++o){
      float2 w = sW[i][ob + o];
      ar[0][o] = fmaf(x0.x, w.x, fmaf(-x0.y, w.y, ar[0][o]));
      ai[0][o] = fmaf(x0.y, w.x, fmaf( x0.x, w.y, ai[0][o]));
      ar[1][o] = fmaf(x1.x, w.x, fmaf(-x1.y, w.y, ar[1][o]));
      ai[1][o] = fmaf(x1.y, w.x, fmaf( x1.x, w.y, ai[1][o]));
    }
  }
  {
    const float* b1r = b1 +       (size_t)h * DH;
    const float* b1i = b1 + 512 + (size_t)h * DH;
    #pragma unroll
    for (int o = 0; o < 4; ++o){
      float br = b1r[ob + o], bi = b1i[ob + o];
      #pragma unroll
      for (int a = 0; a < 2; ++a){
        float gr = gelu_exact(ar[a][o] + br);
        float gi = gelu_exact(ai[a][o] + bi);
        sO[ob + o][fl0 + a] = make_float2(gr, gi);
      }
    }
  }
  __syncthreads();
  // load W2 over W1
  {
    const float* w2r = w2 +           (size_t)h * (DH*DH);
    const float* w2i = w2 + 32768ull + (size_t)h * (DH*DH);
    #pragma unroll
    for (int u = 0; u < 16; ++u){
      int idx = t + 256*u;
      int i = idx >> 6, o = idx & 63;
      sW[i][o] = make_float2(w2r[idx], w2i[idx]);
    }
  }
  __syncthreads();

  #pragma unroll
  for (int a = 0; a < 2; ++a)
    #pragma unroll
    for (int o = 0; o < 4; ++o){ ar[a][o] = 0.f; ai[a][o] = 0.f; }

  // stage 2: o2 = O1 (complex*) W2 + b2
  #pragma unroll 4
  for (int i = 0; i < 64; ++i){
    float2 x0 = sO[i][fl0];
    float2 x1 = sO[i][fl0 + 1];
    #pragma unroll
    for (int o = 0; o < 4; ++o){
      float2 w = sW[i][ob + o];
      ar[0][o] = fmaf(x0.x, w.x, fmaf(-x0.y, w.y, ar[0][o]));
      ai[0][o] = fmaf(x0.y, w.x, fmaf( x0.x, w.y, ai[0][o]));
      ar[1][o] = fmaf(x1.x, w.x, fmaf(-x1.y, w.y, ar[1][o]));
      ai[1][o] = fmaf(x1.y, w.x, fmaf( x1.x, w.y, ai[1][o]));
    }
  }
  {
    const float* b2r = b2 +       (size_t)h * DH;
    const float* b2i = b2 + 512 + (size_t)h * DH;
    #pragma unroll
    for (int o = 0; o < 4; ++o){
      float br = b2r[ob + o], bi = b2i[ob + o];
      #pragma unroll
      for (int a = 0; a < 2; ++a){
        int fglob = F0 + fl0 + a;
        if (fglob < FREQ){
          spec_out[(rowbase + ob + o) * (size_t)FP + fglob] =
              make_float2(ar[a][o] + br, ai[a][o] + bi);
        }
      }
    }
  }
}

// ---------------- launch ----------------
extern "C" void kernel_launch(void* const* d_in, const int* in_sizes, int n_in,
                              void* d_out, int out_size, void* d_ws, size_t ws_size,
                              hipStream_t stream) {
  const float* x  = (const float*)d_in[0];
  const float* w1 = (const float*)d_in[1];
  const float* b1 = (const float*)d_in[2];
  const float* w2 = (const float*)d_in[3];
  const float* b2 = (const float*)d_in[4];
  float* out = (float*)d_out;

  unsigned char* base = (unsigned char*)d_ws;
  if (ws_size < 2 * REGION_BYTES){
    void* p = nullptr;
    hipGetSymbolAddress(&p, HIP_SYMBOL(g_scratch));
    base = (unsigned char*)p;
  }
  float2* specA = (float2*)base;                    // region A: spectrum1, later yt
  unsigned char* regB = base + REGION_BYTES;        // region B: xt, later spectrum2
  float*  xt    = (float*)regB;
  float2* specB = (float2*)regB;
  float*  ytp   = (float*)base;

  // 1) transpose x [B][N][C] -> xt [B][C][N]
  transpose_k<<<dim3(CC/32, NLEN/32, BB), dim3(32, 8), 0, stream>>>(x, xt, NLEN, CC);
  // 2) forward rfft per row
  fft_fwd_k<<<NSEQ, 256, 0, stream>>>(xt, specA);
  // 3) per-frequency two-stage complex MLP
  afno_mid_k<<<dim3(129, HH, BB), 256, 0, stream>>>(specA, specB, w1, b1, w2, b2);
  // 4) inverse rfft per row
  fft_inv_k<<<NSEQ, 256, 0, stream>>>(specB, ytp);
  // 5) transpose yt [B][C][N] -> out [B][N][C]
  transpose_k<<<dim3(NLEN/32, CC/32, BB), dim3(32, 8), 0, stream>>>(ytp, out, CC, NLEN);
}

// Round 2
// 306.856 us; speedup vs baseline: 1.6221x; 1.6221x over previous
//
#include <hip/hip_runtime.h>
#include <math.h>

// ---------------- problem constants ----------------
#define BB    8
#define NLEN  8192          // sequence length (FFT size)
#define CC    512           // channels
#define HH    8             // heads
#define DH    64            // head dim
#define MH    4096          // NLEN/2 (complex FFT size)
#define FREQ  4097          // NLEN/2+1 rfft bins
#define FP    4104          // padded spectrum row length (float2 units)
#define NSEQ  (BB*CC)       // 4096 rows

// scratch: two regions of NSEQ*FP float2
#define REGION_BYTES ((size_t)NSEQ * FP * 8ull)

static __device__ __align__(256) unsigned char g_scratch[2ull * (size_t)NSEQ * FP * 8ull];
// prepped weights: [h][plane(0=w1r,1=w1i,2=w2r,3=w2i)][o][swizzled i] bf16
__device__ unsigned short g_wprep[8 * 4 * 64 * 64];

typedef __attribute__((ext_vector_type(8))) short bf16x8;
typedef __attribute__((ext_vector_type(4))) float f32x4;

__device__ __forceinline__ f32x4 MFMA(bf16x8 a, bf16x8 b, f32x4 c){
  return __builtin_amdgcn_mfma_f32_16x16x32_bf16(a, b, c, 0, 0, 0);
}

__device__ __forceinline__ unsigned short f2bf(float f){
  unsigned u = __float_as_uint(f);
  return (unsigned short)((u + 0x7fffu + ((u >> 16) & 1u)) >> 16);
}
__device__ __forceinline__ unsigned pack2(float a, float b){
  return (unsigned)f2bf(a) | ((unsigned)f2bf(b) << 16);
}

// fast exact-enough GELU: Abramowitz-Stegun 7.1.26 erf (max err 1.5e-7)
__device__ __forceinline__ float gelu_fast(float v){
  float x  = v * 0.70710678118654752440f;
  float ax = fabsf(x);
  float t  = __builtin_amdgcn_rcpf(fmaf(0.3275911f, ax, 1.0f));
  float p  = fmaf(fmaf(fmaf(fmaf(1.061405429f, t, -1.453152027f), t,
                            1.421413741f), t, -0.284496736f), t, 0.254829592f);
  float e  = __expf(-x * x);
  float erf_ax = fmaf(-p * t, e, 1.0f);
  float erfx = copysignf(erf_ax, x);
  return 0.5f * v * (1.0f + erfx);
}

// ---------------- complex helpers ----------------
__device__ __forceinline__ float2 cadd(float2 a, float2 b){ return make_float2(a.x+b.x, a.y+b.y); }
__device__ __forceinline__ float2 csub(float2 a, float2 b){ return make_float2(a.x-b.x, a.y-b.y); }
__device__ __forceinline__ float2 cmul(float2 a, float2 b){
  return make_float2(fmaf(a.x, b.x, -(a.y*b.y)), fmaf(a.x, b.y, a.y*b.x));
}

// ---------------- tiled transpose: per batch slice [R][Cc] -> [Cc][R] ----------------
__global__ __launch_bounds__(256) void transpose_k(const float* __restrict__ in,
                                                   float* __restrict__ out,
                                                   int R, int Cc){
  __shared__ float tile[32][33];
  int b  = blockIdx.z;
  const float* src = in  + (size_t)b * R * Cc;
  float*       dst = out + (size_t)b * R * Cc;
  int c0 = blockIdx.x * 32;
  int r0 = blockIdx.y * 32;
  int tx = threadIdx.x, ty = threadIdx.y;
  #pragma unroll
  for (int k = 0; k < 32; k += 8)
    tile[ty + k][tx] = src[(size_t)(r0 + ty + k) * Cc + c0 + tx];
  __syncthreads();
  #pragma unroll
  for (int k = 0; k < 32; k += 8)
    dst[(size_t)(c0 + ty + k) * R + r0 + tx] = tile[tx][ty + k];
}

// ---------------- Stockham radix-4 pass ----------------
template<int SIGN>
__device__ __forceinline__ void fft_pass(const float2* __restrict__ a,
                                         float2* __restrict__ b,
                                         int Ns, int t){
  #pragma unroll
  for (int q = 0; q < 4; ++q){
    int j = t + 256*q;
    float2 v0 = a[j];
    float2 v1 = a[j + 1024];
    float2 v2 = a[j + 2048];
    float2 v3 = a[j + 3072];
    int jm = j & (Ns - 1);
    float ang = (float)SIGN * 6.2831853071795864769f * (float)jm / (float)(4*Ns);
    float sn, cs; __sincosf(ang, &sn, &cs);
    float2 w1 = make_float2(cs, sn);
    float2 w2 = cmul(w1, w1);
    float2 w3 = cmul(w2, w1);
    v1 = cmul(v1, w1);
    v2 = cmul(v2, w2);
    v3 = cmul(v3, w3);
    float2 s02 = cadd(v0, v2), d02 = csub(v0, v2);
    float2 s13 = cadd(v1, v3), d13 = csub(v1, v3);
    float2 X0 = cadd(s02, s13);
    float2 X2 = csub(s02, s13);
    float2 id = make_float2(-(float)SIGN * d13.y, (float)SIGN * d13.x);
    float2 X1 = cadd(d02, id);
    float2 X3 = csub(d02, id);
    int idxD = ((j - jm) << 2) + jm;
    b[idxD         ] = X0;
    b[idxD +     Ns] = X1;
    b[idxD + 2*Ns  ] = X2;
    b[idxD + 3*Ns  ] = X3;
  }
}

#define ORTHO_S 0.011048543456039806f   // 1/sqrt(8192)

// ---------------- forward rfft-8192 of one contiguous row ----------------
__global__ __launch_bounds__(256) void fft_fwd_k(const float* __restrict__ xt,
                                                 float2* __restrict__ spec){
  __shared__ float2 bufA[MH];
  __shared__ float2 bufB[MH];
  int t = threadIdx.x;
  size_t row = blockIdx.x;
  const float2* src = (const float2*)(xt + row * (size_t)NLEN);
  #pragma unroll
  for (int q = 0; q < 16; ++q) bufA[t + 256*q] = src[t + 256*q];
  __syncthreads();
  float2 *pa = bufA, *pb = bufB;
  #pragma unroll
  for (int p = 0; p < 6; ++p){
    int Ns = 1 << (2*p);
    fft_pass<-1>(pa, pb, Ns, t);
    __syncthreads();
    float2* tmp = pa; pa = pb; pb = tmp;
  }
  float2* dst = spec + row * (size_t)FP;
  #pragma unroll
  for (int q = 0; q < 16; ++q){
    int k = t + 256*q;
    float2 zk = pa[k];
    float2 zc = pa[(MH - k) & (MH - 1)];
    float ex = 0.5f*(zk.x + zc.x);
    float ey = 0.5f*(zk.y - zc.y);
    float ux = zk.x - zc.x;
    float uy = zk.y + zc.y;
    float ox =  0.5f*uy;
    float oy = -0.5f*ux;
    float ang = -6.2831853071795864769f * (float)k / (float)NLEN;
    float sn, cs; __sincosf(ang, &sn, &cs);
    float xr = ex + cs*ox - sn*oy;
    float xi = ey + cs*oy + sn*ox;
    dst[k] = make_float2(ORTHO_S*xr, ORTHO_S*xi);
  }
  if (t == 0){
    float2 z0 = pa[0];
    dst[MH] = make_float2(ORTHO_S*(z0.x - z0.y), 0.0f);
  }
}

// ---------------- inverse rfft-8192 -> one contiguous row ----------------
__global__ __launch_bounds__(256) void fft_inv_k(const float2* __restrict__ spec,
                                                 float* __restrict__ yt){
  __shared__ float2 bufA[MH];
  __shared__ float2 bufB[MH];
  int t = threadIdx.x;
  size_t row = blockIdx.x;
  const float2* src = spec + row * (size_t)FP;
  #pragma unroll
  for (int q = 0; q < 16; ++q){
    int k = t + 256*q;
    float2 xk = src[k];
    float2 xc = src[MH - k];
    if (k == 0){ xk.y = 0.0f; xc.y = 0.0f; }
    float ex = xk.x + xc.x;
    float ey = xk.y - xc.y;
    float dx = xk.x - xc.x;
    float dy = xk.y + xc.y;
    float ang = 6.2831853071795864769f * (float)k / (float)NLEN;
    float sn, cs; __sincosf(ang, &sn, &cs);
    float ox = cs*dx - sn*dy;
    float oy = cs*dy + sn*dx;
    bufA[k] = make_float2(ex - oy, ey + ox);
  }
  __syncthreads();
  float2 *pa = bufA, *pb = bufB;
  #pragma unroll
  for (int p = 0; p < 6; ++p){
    int Ns = 1 << (2*p);
    fft_pass<1>(pa, pb, Ns, t);
    __syncthreads();
    float2* tmp = pa; pa = pb; pb = tmp;
  }
  float2* dst = (float2*)(yt + row * (size_t)NLEN);
  #pragma unroll
  for (int q = 0; q < 16; ++q){
    int m = t + 256*q;
    float2 w = pa[m];
    dst[m] = make_float2(ORTHO_S*w.x, ORTHO_S*w.y);
  }
}

// ---------------- weight prep: transpose + bf16 + swizzle ----------------
// g_wprep[h][p][o][j], j encodes i via 16B-block swizzle: i = ((j>>3)^sw(o))*8 + (j&7)
__global__ __launch_bounds__(256) void wprep_k(const float* __restrict__ w1,
                                               const float* __restrict__ w2){
  int t = threadIdx.x;
  int h = blockIdx.x;
  #pragma unroll 4
  for (int u = 0; u < 64; ++u){
    int idx = t + 256*u;          // p*4096 + o*64 + j
    int p = idx >> 12;
    int o = (idx >> 6) & 63;
    int j = idx & 63;
    int swo = (o ^ (o >> 3)) & 7;
    int i = (((j >> 3) ^ swo) << 3) | (j & 7);
    const float* src = (p < 2) ? w1 : w2;
    float v = src[(size_t)(p & 1) * 32768 + (size_t)h * 4096 + i * 64 + o];
    g_wprep[(size_t)h * 16384 + idx] = f2bf(v);
  }
}

// ---------------- middle: MFMA bf16 two-stage complex MLP ----------------
// block: 128-freq tile x head x batch; 4 waves, wave owns 32 freqs.
// computes O^T = W^T * X^T  (M=o, N=f, K=i), all stage1->stage2 traffic wave-local.
__global__ __launch_bounds__(256) void afno_mid_mfma_k(const float2* __restrict__ spec_in,
                                                       float2* __restrict__ spec_out,
                                                       const float* __restrict__ b1,
                                                       const float* __restrict__ b2){
  __shared__ unsigned short lds[32768];   // XR[128][64] XI[128][64] W1R W1I W2R W2I [64][64]
  const int t  = threadIdx.x;
  const int bx = blockIdx.x, h = blockIdx.y, b = blockIdx.z;
  const int F0 = bx * 128;
  const size_t rowbase = ((size_t)b * HH + h) * DH;

  // ---- stage W: linear 32KB copy of pre-swizzled bf16 weights ----
  {
    const uint4* gw  = (const uint4*)(g_wprep + (size_t)h * 16384);
    uint4*       sw4 = (uint4*)(lds + 16384);
    #pragma unroll
    for (int u = 0; u < 8; ++u) sw4[t + 256*u] = gw[t + 256*u];
  }
  // ---- stage X: global [i][f] -> LDS bf16 [f][i] with 16B-block swizzle ----
  {
    const int l = t & 63, wv = t >> 6;
    const int fl = l & 15, g = l >> 4;       // g in 0..3
    #pragma unroll
    for (int it = 0; it < 16; ++it){
      int ci = wv + 4*it;                    // 0..63
      int fc = ci & 7, pc = ci >> 3;         // f-chunk, i-chunk
      int f  = fc*16 + fl;
      int i0 = pc*8 + g*2;
      int fglob = F0 + f;
      float2 v0 = make_float2(0.f, 0.f), v1 = make_float2(0.f, 0.f);
      if (fglob < FREQ){
        v0 = spec_in[(rowbase + i0    ) * (size_t)FP + fglob];
        v1 = spec_in[(rowbase + i0 + 1) * (size_t)FP + fglob];
      }
      int swf = (f ^ (f >> 3)) & 7;
      int j0  = ((((i0 >> 3) ^ swf) << 3) | (i0 & 7));
      *(unsigned*)(lds        + f*64 + j0) = pack2(v0.x, v1.x);
      *(unsigned*)(lds + 8192 + f*64 + j0) = pack2(v0.y, v1.y);
    }
  }
  __syncthreads();

  const int l  = t & 63, wv = t >> 6;
  const int wf0 = wv * 32;
  const int lf = l & 15, lg = l >> 4;
  const unsigned short* XR  = lds;
  const unsigned short* XI  = lds + 8192;
  const unsigned short* W1R = lds + 16384;
  const unsigned short* W1I = lds + 20480;
  const unsigned short* W2R = lds + 24576;
  const unsigned short* W2I = lds + 28672;

  f32x4 aR[4][2], aI[4][2];
  const f32x4 zz = {0.f, 0.f, 0.f, 0.f};
  #pragma unroll
  for (int mt = 0; mt < 4; ++mt)
    #pragma unroll
    for (int nt = 0; nt < 2; ++nt){ aR[mt][nt] = zz; aI[mt][nt] = zz; }

  // -------- stage 1: O1^T = W1^T X^T --------
  #pragma unroll
  for (int ks = 0; ks < 2; ++ks){
    int b0 = ks*4 + lg;
    bf16x8 awr[4], awi[4], awin[4];
    #pragma unroll
    for (int mt = 0; mt < 4; ++mt){
      int o = mt*16 + lf;
      int swo = (o ^ (o >> 3)) & 7;
      int off = o*64 + ((b0 ^ swo) << 3);
      awr[mt]  = *(const bf16x8*)(W1R + off);
      awi[mt]  = *(const bf16x8*)(W1I + off);
      awin[mt] = awi[mt] ^ (short)0x8000;
    }
    bf16x8 bxr[2], bxi[2];
    #pragma unroll
    for (int nt = 0; nt < 2; ++nt){
      int f = wf0 + nt*16 + lf;
      int swf = (f ^ (f >> 3)) & 7;
      int off = f*64 + ((b0 ^ swf) << 3);
      bxr[nt] = *(const bf16x8*)(XR + off);
      bxi[nt] = *(const bf16x8*)(XI + off);
    }
    #pragma unroll
    for (int mt = 0; mt < 4; ++mt)
      #pragma unroll
      for (int nt = 0; nt < 2; ++nt){
        aR[mt][nt] = MFMA(awr[mt],  bxr[nt], aR[mt][nt]);
        aR[mt][nt] = MFMA(awin[mt], bxi[nt], aR[mt][nt]);
        aI[mt][nt] = MFMA(awi[mt],  bxr[nt], aI[mt][nt]);
        aI[mt][nt] = MFMA(awr[mt],  bxi[nt], aI[mt][nt]);
      }
  }

  // -------- stage-1 epilogue: bias + GELU -> bf16 O planes (reuse X planes) --------
  #pragma unroll
  for (int mt = 0; mt < 4; ++mt){
    int o0 = mt*16 + lg*4;
    float4 br = *(const float4*)(b1 +       (size_t)h*64 + o0);
    float4 bi = *(const float4*)(b1 + 512 + (size_t)h*64 + o0);
    #pragma unroll
    for (int nt = 0; nt < 2; ++nt){
      int f = wf0 + nt*16 + lf;
      int swf = (f ^ (f >> 3)) & 7;
      int j0 = ((((o0 >> 3) ^ swf) << 3) | (o0 & 7));
      uint2 pr, pi;
      pr.x = pack2(gelu_fast(aR[mt][nt][0] + br.x), gelu_fast(aR[mt][nt][1] + br.y));
      pr.y = pack2(gelu_fast(aR[mt][nt][2] + br.z), gelu_fast(aR[mt][nt][3] + br.w));
      pi.x = pack2(gelu_fast(aI[mt][nt][0] + bi.x), gelu_fast(aI[mt][nt][1] + bi.y));
      pi.y = pack2(gelu_fast(aI[mt][nt][2] + bi.z), gelu_fast(aI[mt][nt][3] + bi.w));
      *(uint2*)(lds        + f*64 + j0) = pr;
      *(uint2*)(lds + 8192 + f*64 + j0) = pi;
    }
  }

  // -------- stage 2: O2^T = W2^T O1^T --------
  #pragma unroll
  for (int mt = 0; mt < 4; ++mt)
    #pragma unroll
    for (int nt = 0; nt < 2; ++nt){ aR[mt][nt] = zz; aI[mt][nt] = zz; }

  #pragma unroll
  for (int ks = 0; ks < 2; ++ks){
    int b0 = ks*4 + lg;
    bf16x8 awr[4], awi[4], awin[4];
    #pragma unroll
    for (int mt = 0; mt < 4; ++mt){
      int o = mt*16 + lf;
      int swo = (o ^ (o >> 3)) & 7;
      int off = o*64 + ((b0 ^ swo) << 3);
      awr[mt]  = *(const bf16x8*)(W2R + off);
      awi[mt]  = *(const bf16x8*)(W2I + off);
      awin[mt] = awi[mt] ^ (short)0x8000;
    }
    bf16x8 bxr[2], bxi[2];
    #pragma unroll
    for (int nt = 0; nt < 2; ++nt){
      int f = wf0 + nt*16 + lf;
      int swf = (f ^ (f >> 3)) & 7;
      int off = f*64 + ((b0 ^ swf) << 3);
      bxr[nt] = *(const bf16x8*)(XR + off);
      bxi[nt] = *(const bf16x8*)(XI + off);
    }
    #pragma unroll
    for (int mt = 0; mt < 4; ++mt)
      #pragma unroll
      for (int nt = 0; nt < 2; ++nt){
        aR[mt][nt] = MFMA(awr[mt],  bxr[nt], aR[mt][nt]);
        aR[mt][nt] = MFMA(awin[mt], bxi[nt], aR[mt][nt]);
        aI[mt][nt] = MFMA(awi[mt],  bxr[nt], aI[mt][nt]);
        aI[mt][nt] = MFMA(awr[mt],  bxi[nt], aI[mt][nt]);
      }
  }

  // -------- stage-2 epilogue: bias + store --------
  #pragma unroll
  for (int mt = 0; mt < 4; ++mt){
    int o0 = mt*16 + lg*4;
    float4 br = *(const float4*)(b2 +       (size_t)h*64 + o0);
    float4 bi = *(const float4*)(b2 + 512 + (size_t)h*64 + o0);
    #pragma unroll
    for (int nt = 0; nt < 2; ++nt){
      int fglob = F0 + wf0 + nt*16 + lf;
      if (fglob < FREQ){
        float brr[4] = {br.x, br.y, br.z, br.w};
        float bii[4] = {bi.x, bi.y, bi.z, bi.w};
        #pragma unroll
        for (int r = 0; r < 4; ++r){
          spec_out[(rowbase + o0 + r) * (size_t)FP + fglob] =
              make_float2(aR[mt][nt][r] + brr[r], aI[mt][nt][r] + bii[r]);
        }
      }
    }
  }
}

// ---------------- launch ----------------
extern "C" void kernel_launch(void* const* d_in, const int* in_sizes, int n_in,
                              void* d_out, int out_size, void* d_ws, size_t ws_size,
                              hipStream_t stream) {
  const float* x  = (const float*)d_in[0];
  const float* w1 = (const float*)d_in[1];
  const float* b1 = (const float*)d_in[2];
  const float* w2 = (const float*)d_in[3];
  const float* b2 = (const float*)d_in[4];
  float* out = (float*)d_out;

  unsigned char* base = (unsigned char*)d_ws;
  if (ws_size < 2 * REGION_BYTES){
    void* p = nullptr;
    hipGetSymbolAddress(&p, HIP_SYMBOL(g_scratch));
    base = (unsigned char*)p;
  }
  float2* specA = (float2*)base;                    // region A: spectrum1, later yt
  unsigned char* regB = base + REGION_BYTES;        // region B: xt, later spectrum2
  float*  xt    = (float*)regB;
  float2* specB = (float2*)regB;
  float*  ytp   = (float*)base;

  // 0) weight prep (bf16 + transpose + swizzle)
  wprep_k<<<8, 256, 0, stream>>>(w1, w2);
  // 1) transpose x [B][N][C] -> xt [B][C][N]
  transpose_k<<<dim3(CC/32, NLEN/32, BB), dim3(32, 8), 0, stream>>>(x, xt, NLEN, CC);
  // 2) forward rfft per row
  fft_fwd_k<<<NSEQ, 256, 0, stream>>>(xt, specA);
  // 3) per-frequency two-stage complex MLP (bf16 MFMA)
  afno_mid_mfma_k<<<dim3(33, HH, BB), 256, 0, stream>>>(specA, specB, b1, b2);
  // 4) inverse rfft per row
  fft_inv_k<<<NSEQ, 256, 0, stream>>>(specB, ytp);
  // 5) transpose yt [B][C][N] -> out [B][N][C]
  transpose_k<<<dim3(NLEN/32, CC/32, BB), dim3(32, 8), 0, stream>>>(ytp, out, CC, NLEN);
}

// Round 4
// 254.937 us; speedup vs baseline: 1.9525x; 1.2037x over previous
//
#include <hip/hip_runtime.h>
#include <math.h>

// ---------------- problem constants ----------------
#define BB    8
#define NLEN  8192          // sequence length (FFT size)
#define CC    512           // channels
#define HH    8             // heads
#define DH    64            // head dim
#define MH    4096          // NLEN/2 (complex FFT size)
#define FREQ  4097          // rfft bins
#define FP    4104          // padded spectrum row length (uint bins)
#define NSEQ  (BB*CC)       // 4096 rows

// scratch: two regions of NSEQ*FP uint (bf16 (r,i) packed bins)
#define REGION_BYTES ((size_t)NSEQ * FP * 4ull)

static __device__ __align__(256) unsigned char g_scratch[2ull * (size_t)NSEQ * FP * 4ull];
// prepped weights: [h][plane(0=w1r,1=w1i,2=w2r,3=w2i)][o][swizzled i] bf16
__device__ unsigned short g_wprep[8 * 4 * 64 * 64];

typedef __attribute__((ext_vector_type(8))) short bf16x8;
typedef __attribute__((ext_vector_type(4))) float f32x4;

__device__ __forceinline__ f32x4 MFMA(bf16x8 a, bf16x8 b, f32x4 c){
  return __builtin_amdgcn_mfma_f32_16x16x32_bf16(a, b, c, 0, 0, 0);
}

__device__ __forceinline__ unsigned short f2bf(float f){
  unsigned u = __float_as_uint(f);
  return (unsigned short)((u + 0x7fffu + ((u >> 16) & 1u)) >> 16);
}
__device__ __forceinline__ unsigned pack2(float a, float b){
  return (unsigned)f2bf(a) | ((unsigned)f2bf(b) << 16);
}
__device__ __forceinline__ float bflo(unsigned u){ return __uint_as_float(u << 16); }
__device__ __forceinline__ float bfhi(unsigned u){ return __uint_as_float(u & 0xffff0000u); }

// LDS bank swizzle for FFT buffers (float2-index): spreads Stockham small-Ns
// write strides across banks; bijective within each 256-element span.
#define IDX(i) ((i) ^ (((i) >> 4) & 15))

// fast exact-enough GELU: Abramowitz-Stegun 7.1.26 erf (max err 1.5e-7)
__device__ __forceinline__ float gelu_fast(float v){
  float x  = v * 0.70710678118654752440f;
  float ax = fabsf(x);
  float t  = __builtin_amdgcn_rcpf(fmaf(0.3275911f, ax, 1.0f));
  float p  = fmaf(fmaf(fmaf(fmaf(1.061405429f, t, -1.453152027f), t,
                            1.421413741f), t, -0.284496736f), t, 0.254829592f);
  float e  = __expf(-x * x);
  float erf_ax = fmaf(-p * t, e, 1.0f);
  float erfx = copysignf(erf_ax, x);
  return 0.5f * v * (1.0f + erfx);
}

// ---------------- complex helpers ----------------
__device__ __forceinline__ float2 cadd(float2 a, float2 b){ return make_float2(a.x+b.x, a.y+b.y); }
__device__ __forceinline__ float2 csub(float2 a, float2 b){ return make_float2(a.x-b.x, a.y-b.y); }
__device__ __forceinline__ float2 cmul(float2 a, float2 b){
  return make_float2(fmaf(a.x, b.x, -(a.y*b.y)), fmaf(a.x, b.y, a.y*b.x));
}

// ---------------- transpose 1: x [B][N][C] fp32 -> xt [B][C][N] bf16 ----------------
__global__ __launch_bounds__(256) void transpose_in_k(const float* __restrict__ in,
                                                      unsigned* __restrict__ out){
  __shared__ float tile[64][33];
  int b  = blockIdx.z;
  int c0 = blockIdx.x * 32;
  int n0 = blockIdx.y * 64;
  int t  = threadIdx.x;
  int tx = t & 31, ty = t >> 5;
  const float* src = in + ((size_t)b * NLEN + n0) * CC + c0;
  #pragma unroll
  for (int k = 0; k < 8; ++k)
    tile[ty + 8*k][tx] = src[(size_t)(ty + 8*k) * CC + tx];
  __syncthreads();
  int lt = t & 15;
  int nl = 4 * lt;
  #pragma unroll
  for (int kk = 0; kk < 2; ++kk){
    int cl = (t >> 4) + 16*kk;
    uint2 u;
    u.x = pack2(tile[nl    ][cl], tile[nl + 1][cl]);
    u.y = pack2(tile[nl + 2][cl], tile[nl + 3][cl]);
    *(uint2*)(out + ((size_t)(b * CC + c0 + cl) * NLEN + n0) / 2 + 2*lt) = u;
  }
}

// ---------------- transpose 2: yt [B][C][N] bf16 -> out [B][N][C] fp32 ----------------
__global__ __launch_bounds__(256) void transpose_out_k(const unsigned* __restrict__ in,
                                                       float* __restrict__ out){
  __shared__ float tile[64][33];
  int b  = blockIdx.z;
  int c0 = blockIdx.x * 32;
  int n0 = blockIdx.y * 64;
  int t  = threadIdx.x;
  int lt = t & 15;
  int nl = 4 * lt;
  #pragma unroll
  for (int kk = 0; kk < 2; ++kk){
    int cl = (t >> 4) + 16*kk;
    uint2 u = *(const uint2*)(in + ((size_t)(b * CC + c0 + cl) * NLEN + n0) / 2 + 2*lt);
    tile[nl    ][cl] = bflo(u.x);
    tile[nl + 1][cl] = bfhi(u.x);
    tile[nl + 2][cl] = bflo(u.y);
    tile[nl + 3][cl] = bfhi(u.y);
  }
  __syncthreads();
  int tx = t & 31, ty = t >> 5;
  float* dst = out + ((size_t)b * NLEN + n0) * CC + c0;
  #pragma unroll
  for (int k = 0; k < 8; ++k)
    dst[(size_t)(ty + 8*k) * CC + tx] = tile[ty + 8*k][tx];
}

// ---------------- Stockham radix-4 pass (512 threads, swizzled LDS) ----------------
template<int SIGN>
__device__ __forceinline__ void fft_pass(const float2* __restrict__ a,
                                         float2* __restrict__ b,
                                         int Ns, int t){
  #pragma unroll
  for (int q = 0; q < 2; ++q){
    int j = t + 512*q;
    float2 v0 = a[IDX(j)];
    float2 v1 = a[IDX(j + 1024)];
    float2 v2 = a[IDX(j + 2048)];
    float2 v3 = a[IDX(j + 3072)];
    int jm = j & (Ns - 1);
    float ang = (float)SIGN * 6.2831853071795864769f * (float)jm / (float)(4*Ns);
    float sn, cs; __sincosf(ang, &sn, &cs);
    float2 w1 = make_float2(cs, sn);
    float2 w2 = cmul(w1, w1);
    float2 w3 = cmul(w2, w1);
    v1 = cmul(v1, w1);
    v2 = cmul(v2, w2);
    v3 = cmul(v3, w3);
    float2 s02 = cadd(v0, v2), d02 = csub(v0, v2);
    float2 s13 = cadd(v1, v3), d13 = csub(v1, v3);
    float2 X0 = cadd(s02, s13);
    float2 X2 = csub(s02, s13);
    float2 id = make_float2(-(float)SIGN * d13.y, (float)SIGN * d13.x);
    float2 X1 = cadd(d02, id);
    float2 X3 = csub(d02, id);
    int idxD = ((j - jm) << 2) + jm;
    b[IDX(idxD       )] = X0;
    b[IDX(idxD +   Ns)] = X1;
    b[IDX(idxD + 2*Ns)] = X2;
    b[IDX(idxD + 3*Ns)] = X3;
  }
}

#define ORTHO_S 0.011048543456039806f   // 1/sqrt(8192)

// ---------------- forward rfft-8192: xt bf16 row -> spec bf16 bins ----------------
__global__ __launch_bounds__(512) void fft_fwd_k(const unsigned* __restrict__ xt,
                                                 unsigned* __restrict__ spec){
  __shared__ float2 bufA[MH];
  __shared__ float2 bufB[MH];
  int t = threadIdx.x;
  size_t row = blockIdx.x;
  const unsigned* src = xt + row * (NLEN/2);
  #pragma unroll
  for (int q = 0; q < 8; ++q){
    int m = t + 512*q;
    unsigned u = src[m];
    bufA[IDX(m)] = make_float2(bflo(u), bfhi(u));   // z[m] = x[2m] + i x[2m+1]
  }
  __syncthreads();
  float2 *pa = bufA, *pb = bufB;
  #pragma unroll
  for (int p = 0; p < 6; ++p){
    int Ns = 1 << (2*p);
    fft_pass<-1>(pa, pb, Ns, t);
    __syncthreads();
    float2* tmp = pa; pa = pb; pb = tmp;
  }
  unsigned* dst = spec + row * (size_t)FP;
  #pragma unroll
  for (int q = 0; q < 8; ++q){
    int k = t + 512*q;
    float2 zk = pa[IDX(k)];
    float2 zc = pa[IDX((MH - k) & (MH - 1))];
    float ex = 0.5f*(zk.x + zc.x);
    float ey = 0.5f*(zk.y - zc.y);
    float ux = zk.x - zc.x;
    float uy = zk.y + zc.y;
    float ox =  0.5f*uy;
    float oy = -0.5f*ux;
    float ang = -6.2831853071795864769f * (float)k / (float)NLEN;
    float sn, cs; __sincosf(ang, &sn, &cs);
    float xr = ex + cs*ox - sn*oy;
    float xi = ey + cs*oy + sn*ox;
    dst[k] = pack2(ORTHO_S*xr, ORTHO_S*xi);
  }
  if (t == 0){
    float2 z0 = pa[IDX(0)];
    dst[MH] = pack2(ORTHO_S*(z0.x - z0.y), 0.0f);   // Nyquist (real)
  }
}

// ---------------- inverse rfft-8192: spec bf16 bins -> yt bf16 row ----------------
__global__ __launch_bounds__(512) void fft_inv_k(const unsigned* __restrict__ spec,
                                                 unsigned* __restrict__ yt){
  __shared__ float2 bufA[MH];
  __shared__ float2 bufB[MH];
  int t = threadIdx.x;
  size_t row = blockIdx.x;
  const unsigned* src = spec + row * (size_t)FP;
  #pragma unroll
  for (int q = 0; q < 8; ++q){
    int k = t + 512*q;
    unsigned uk = src[k];
    unsigned uc = src[MH - k];
    float2 xk = make_float2(bflo(uk), bfhi(uk));
    float2 xc = make_float2(bflo(uc), bfhi(uc));
    if (k == 0){ xk.y = 0.0f; xc.y = 0.0f; }        // drop imag at DC/Nyquist
    float ex = xk.x + xc.x;
    float ey = xk.y - xc.y;
    float dx = xk.x - xc.x;
    float dy = xk.y + xc.y;
    float ang = 6.2831853071795864769f * (float)k / (float)NLEN;
    float sn, cs; __sincosf(ang, &sn, &cs);
    float ox = cs*dx - sn*dy;
    float oy = cs*dy + sn*dx;
    bufA[IDX(k)] = make_float2(ex - oy, ey + ox);
  }
  __syncthreads();
  float2 *pa = bufA, *pb = bufB;
  #pragma unroll
  for (int p = 0; p < 6; ++p){
    int Ns = 1 << (2*p);
    fft_pass<1>(pa, pb, Ns, t);
    __syncthreads();
    float2* tmp = pa; pa = pb; pb = tmp;
  }
  unsigned* dst = yt + row * (NLEN/2);
  #pragma unroll
  for (int q = 0; q < 8; ++q){
    int m = t + 512*q;
    float2 w = pa[IDX(m)];
    dst[m] = pack2(ORTHO_S*w.x, ORTHO_S*w.y);       // y[2m], y[2m+1]
  }
}

// ---------------- weight prep: transpose + bf16 + swizzle ----------------
__global__ __launch_bounds__(256) void wprep_k(const float* __restrict__ w1,
                                               const float* __restrict__ w2){
  int t = threadIdx.x;
  int h = blockIdx.x;
  #pragma unroll 4
  for (int u = 0; u < 64; ++u){
    int idx = t + 256*u;          // p*4096 + o*64 + j
    int p = idx >> 12;
    int o = (idx >> 6) & 63;
    int j = idx & 63;
    int swo = (o ^ (o >> 3)) & 7;
    int i = (((j >> 3) ^ swo) << 3) | (j & 7);
    const float* src = (p < 2) ? w1 : w2;
    float v = src[(size_t)(p & 1) * 32768 + (size_t)h * 4096 + i * 64 + o];
    g_wprep[(size_t)h * 16384 + idx] = f2bf(v);
  }
}

// ---------------- middle: MFMA bf16 two-stage complex MLP ----------------
// block: 128-freq tile x head x batch; 4 waves, wave owns 32 freqs.
// O^T = W^T * X^T (M=o, N=f, K=i); stage1->stage2 traffic wave-local.
__global__ __launch_bounds__(256) void afno_mid_mfma_k(const unsigned* __restrict__ spec_in,
                                                       unsigned* __restrict__ spec_out,
                                                       const float* __restrict__ b1,
                                                       const float* __restrict__ b2){
  __shared__ unsigned short lds[32768];   // XR[128][64] XI[128][64] W1R W1I W2R W2I [64][64]
  const int t  = threadIdx.x;
  const int bx = blockIdx.x, h = blockIdx.y, b = blockIdx.z;
  const int F0 = bx * 128;
  const size_t rowbase = ((size_t)b * HH + h) * DH;

  // ---- stage W: linear 32KB copy of pre-swizzled bf16 weights ----
  {
    const uint4* gw  = (const uint4*)(g_wprep + (size_t)h * 16384);
    uint4*       sw4 = (uint4*)(lds + 16384);
    #pragma unroll
    for (int u = 0; u < 8; ++u) sw4[t + 256*u] = gw[t + 256*u];
  }
  // ---- stage X: global bf16 bins [i][f] -> LDS planes [f][i] (16B-block swizzle) ----
  {
    const int l = t & 63, wv = t >> 6;
    const int fl = l & 15, g = l >> 4;       // g in 0..3
    #pragma unroll
    for (int it = 0; it < 16; ++it){
      int ci = wv + 4*it;                    // 0..63
      int fc = ci & 7, pc = ci >> 3;
      int f  = fc*16 + fl;
      int i0 = pc*8 + g*2;
      int fglob = F0 + f;
      unsigned u0 = 0, u1 = 0;
      if (fglob < FREQ){
        u0 = spec_in[(rowbase + i0    ) * (size_t)FP + fglob];
        u1 = spec_in[(rowbase + i0 + 1) * (size_t)FP + fglob];
      }
      unsigned wr = __builtin_amdgcn_perm(u1, u0, 0x05040100u);  // r(i0), r(i0+1)
      unsigned wi = __builtin_amdgcn_perm(u1, u0, 0x07060302u);  // i(i0), i(i0+1)
      int swf = (f ^ (f >> 3)) & 7;
      int j0  = ((((i0 >> 3) ^ swf) << 3) | (i0 & 7));
      *(unsigned*)(lds        + f*64 + j0) = wr;
      *(unsigned*)(lds + 8192 + f*64 + j0) = wi;
    }
  }
  __syncthreads();

  const int l  = t & 63, wv = t >> 6;
  const int wf0 = wv * 32;
  const int lf = l & 15, lg = l >> 4;
  const unsigned short* XR  = lds;
  const unsigned short* XI  = lds + 8192;
  const unsigned short* W1R = lds + 16384;
  const unsigned short* W1I = lds + 20480;
  const unsigned short* W2R = lds + 24576;
  const unsigned short* W2I = lds + 28672;

  f32x4 aR[4][2], aI[4][2];
  const f32x4 zz = {0.f, 0.f, 0.f, 0.f};
  #pragma unroll
  for (int mt = 0; mt < 4; ++mt)
    #pragma unroll
    for (int nt = 0; nt < 2; ++nt){ aR[mt][nt] = zz; aI[mt][nt] = zz; }

  // -------- stage 1: O1^T = W1^T X^T --------
  #pragma unroll
  for (int ks = 0; ks < 2; ++ks){
    int b0 = ks*4 + lg;
    bf16x8 awr[4], awi[4], awin[4];
    #pragma unroll
    for (int mt = 0; mt < 4; ++mt){
      int o = mt*16 + lf;
      int swo = (o ^ (o >> 3)) & 7;
      int off = o*64 + ((b0 ^ swo) << 3);
      awr[mt]  = *(const bf16x8*)(W1R + off);
      awi[mt]  = *(const bf16x8*)(W1I + off);
      awin[mt] = awi[mt] ^ (short)0x8000;
    }
    bf16x8 bxr[2], bxi[2];
    #pragma unroll
    for (int nt = 0; nt < 2; ++nt){
      int f = wf0 + nt*16 + lf;
      int swf = (f ^ (f >> 3)) & 7;
      int off = f*64 + ((b0 ^ swf) << 3);
      bxr[nt] = *(const bf16x8*)(XR + off);
      bxi[nt] = *(const bf16x8*)(XI + off);
    }
    #pragma unroll
    for (int mt = 0; mt < 4; ++mt)
      #pragma unroll
      for (int nt = 0; nt < 2; ++nt){
        aR[mt][nt] = MFMA(awr[mt],  bxr[nt], aR[mt][nt]);
        aR[mt][nt] = MFMA(awin[mt], bxi[nt], aR[mt][nt]);
        aI[mt][nt] = MFMA(awi[mt],  bxr[nt], aI[mt][nt]);
        aI[mt][nt] = MFMA(awr[mt],  bxi[nt], aI[mt][nt]);
      }
  }

  // -------- stage-1 epilogue: bias + GELU -> bf16 O planes (reuse X planes) --------
  #pragma unroll
  for (int mt = 0; mt < 4; ++mt){
    int o0 = mt*16 + lg*4;
    float4 br = *(const float4*)(b1 +       (size_t)h*64 + o0);
    float4 bi = *(const float4*)(b1 + 512 + (size_t)h*64 + o0);
    #pragma unroll
    for (int nt = 0; nt < 2; ++nt){
      int f = wf0 + nt*16 + lf;
      int swf = (f ^ (f >> 3)) & 7;
      int j0 = ((((o0 >> 3) ^ swf) << 3) | (o0 & 7));
      uint2 pr, pi;
      pr.x = pack2(gelu_fast(aR[mt][nt][0] + br.x), gelu_fast(aR[mt][nt][1] + br.y));
      pr.y = pack2(gelu_fast(aR[mt][nt][2] + br.z), gelu_fast(aR[mt][nt][3] + br.w));
      pi.x = pack2(gelu_fast(aI[mt][nt][0] + bi.x), gelu_fast(aI[mt][nt][1] + bi.y));
      pi.y = pack2(gelu_fast(aI[mt][nt][2] + bi.z), gelu_fast(aI[mt][nt][3] + bi.w));
      *(uint2*)(lds        + f*64 + j0) = pr;
      *(uint2*)(lds + 8192 + f*64 + j0) = pi;
    }
  }

  // -------- stage 2: O2^T = W2^T O1^T --------
  #pragma unroll
  for (int mt = 0; mt < 4; ++mt)
    #pragma unroll
    for (int nt = 0; nt < 2; ++nt){ aR[mt][nt] = zz; aI[mt][nt] = zz; }

  #pragma unroll
  for (int ks = 0; ks < 2; ++ks){
    int b0 = ks*4 + lg;
    bf16x8 awr[4], awi[4], awin[4];
    #pragma unroll
    for (int mt = 0; mt < 4; ++mt){
      int o = mt*16 + lf;
      int swo = (o ^ (o >> 3)) & 7;
      int off = o*64 + ((b0 ^ swo) << 3);
      awr[mt]  = *(const bf16x8*)(W2R + off);
      awi[mt]  = *(const bf16x8*)(W2I + off);
      awin[mt] = awi[mt] ^ (short)0x8000;
    }
    bf16x8 bxr[2], bxi[2];
    #pragma unroll
    for (int nt = 0; nt < 2; ++nt){
      int f = wf0 + nt*16 + lf;
      int swf = (f ^ (f >> 3)) & 7;
      int off = f*64 + ((b0 ^ swf) << 3);
      bxr[nt] = *(const bf16x8*)(XR + off);
      bxi[nt] = *(const bf16x8*)(XI + off);
    }
    #pragma unroll
    for (int mt = 0; mt < 4; ++mt)
      #pragma unroll
      for (int nt = 0; nt < 2; ++nt){
        aR[mt][nt] = MFMA(awr[mt],  bxr[nt], aR[mt][nt]);
        aR[mt][nt] = MFMA(awin[mt], bxi[nt], aR[mt][nt]);
        aI[mt][nt] = MFMA(awi[mt],  bxr[nt], aI[mt][nt]);
        aI[mt][nt] = MFMA(awr[mt],  bxi[nt], aI[mt][nt]);
      }
  }

  // -------- stage-2 epilogue: bias + bf16 store --------
  #pragma unroll
  for (int mt = 0; mt < 4; ++mt){
    int o0 = mt*16 + lg*4;
    float4 br = *(const float4*)(b2 +       (size_t)h*64 + o0);
    float4 bi = *(const float4*)(b2 + 512 + (size_t)h*64 + o0);
    #pragma unroll
    for (int nt = 0; nt < 2; ++nt){
      int fglob = F0 + wf0 + nt*16 + lf;
      if (fglob < FREQ){
        float brr[4] = {br.x, br.y, br.z, br.w};
        float bii[4] = {bi.x, bi.y, bi.z, bi.w};
        #pragma unroll
        for (int r = 0; r < 4; ++r){
          spec_out[(rowbase + o0 + r) * (size_t)FP + fglob] =
              pack2(aR[mt][nt][r] + brr[r], aI[mt][nt][r] + bii[r]);
        }
      }
    }
  }
}

// ---------------- launch ----------------
extern "C" void kernel_launch(void* const* d_in, const int* in_sizes, int n_in,
                              void* d_out, int out_size, void* d_ws, size_t ws_size,
                              hipStream_t stream) {
  const float* x  = (const float*)d_in[0];
  const float* w1 = (const float*)d_in[1];
  const float* b1 = (const float*)d_in[2];
  const float* w2 = (const float*)d_in[3];
  const float* b2 = (const float*)d_in[4];
  float* out = (float*)d_out;

  unsigned char* base = (unsigned char*)d_ws;
  if (ws_size < 2 * REGION_BYTES){
    void* p = nullptr;
    hipGetSymbolAddress(&p, HIP_SYMBOL(g_scratch));
    base = (unsigned char*)p;
  }
  unsigned* specA = (unsigned*)base;                 // region A: spectrum1, later yt
  unsigned char* regB = base + REGION_BYTES;         // region B: xt, later spectrum2
  unsigned* xt    = (unsigned*)regB;
  unsigned* specB = (unsigned*)regB;
  unsigned* ytp   = (unsigned*)base;

  // 0) weight prep (bf16 + transpose + swizzle)
  wprep_k<<<8, 256, 0, stream>>>(w1, w2);
  // 1) transpose x [B][N][C] fp32 -> xt [B][C][N] bf16
  transpose_in_k<<<dim3(CC/32, NLEN/64, BB), 256, 0, stream>>>(x, xt);
  // 2) forward rfft per row
  fft_fwd_k<<<NSEQ, 512, 0, stream>>>(xt, specA);
  // 3) per-frequency two-stage complex MLP (bf16 MFMA)
  afno_mid_mfma_k<<<dim3(33, HH, BB), 256, 0, stream>>>(specA, specB, b1, b2);
  // 4) inverse rfft per row
  fft_inv_k<<<NSEQ, 512, 0, stream>>>(specB, ytp);
  // 5) transpose yt [B][C][N] bf16 -> out [B][N][C] fp32
  transpose_out_k<<<dim3(CC/32, NLEN/64, BB), 256, 0, stream>>>(ytp, out);
}

// Round 5
// 234.362 us; speedup vs baseline: 2.1239x; 1.0878x over previous
//
#include <hip/hip_runtime.h>
#include <math.h>

// ---------------- problem constants ----------------
#define BB    8
#define NLEN  8192          // sequence length (FFT size)
#define CC    512           // channels
#define HH    8             // heads
#define DH    64            // head dim
#define MH    4096          // NLEN/2 (complex FFT size)
#define FREQ  4097          // rfft bins
#define FP    4104          // padded spectrum row length (uint bins)
#define NSEQ  (BB*CC)       // 4096 rows

// scratch: two regions of NSEQ*FP uint (bf16 (r,i) packed bins)
#define REGION_BYTES ((size_t)NSEQ * FP * 4ull)

static __device__ __align__(256) unsigned char g_scratch[2ull * (size_t)NSEQ * FP * 4ull];
// prepped weights: [h][plane(0=w1r,1=w1i,2=w2r,3=w2i)][o][swizzled k-slot] bf16
__device__ unsigned short g_wprep[8 * 4 * 64 * 64];

typedef __attribute__((ext_vector_type(8))) short bf16x8;
typedef __attribute__((ext_vector_type(4))) float f32x4;

__device__ __forceinline__ f32x4 MFMA(bf16x8 a, bf16x8 b, f32x4 c){
  return __builtin_amdgcn_mfma_f32_16x16x32_bf16(a, b, c, 0, 0, 0);
}

__device__ __forceinline__ unsigned short f2bf(float f){
  unsigned u = __float_as_uint(f);
  return (unsigned short)((u + 0x7fffu + ((u >> 16) & 1u)) >> 16);
}
__device__ __forceinline__ unsigned pack2(float a, float b){
  return (unsigned)f2bf(a) | ((unsigned)f2bf(b) << 16);
}
__device__ __forceinline__ float bflo(unsigned u){ return __uint_as_float(u << 16); }
__device__ __forceinline__ float bfhi(unsigned u){ return __uint_as_float(u & 0xffff0000u); }

// LDS bank swizzle for FFT buffers (float2-index)
#define IDX(i) ((i) ^ (((i) >> 4) & 15))

// fast exact-enough GELU: Abramowitz-Stegun 7.1.26 erf (max err 1.5e-7)
__device__ __forceinline__ float gelu_fast(float v){
  float x  = v * 0.70710678118654752440f;
  float ax = fabsf(x);
  float t  = __builtin_amdgcn_rcpf(fmaf(0.3275911f, ax, 1.0f));
  float p  = fmaf(fmaf(fmaf(fmaf(1.061405429f, t, -1.453152027f), t,
                            1.421413741f), t, -0.284496736f), t, 0.254829592f);
  float e  = __expf(-x * x);
  float erf_ax = fmaf(-p * t, e, 1.0f);
  float erfx = copysignf(erf_ax, x);
  return 0.5f * v * (1.0f + erfx);
}

// ---------------- complex helpers ----------------
__device__ __forceinline__ float2 cadd(float2 a, float2 b){ return make_float2(a.x+b.x, a.y+b.y); }
__device__ __forceinline__ float2 csub(float2 a, float2 b){ return make_float2(a.x-b.x, a.y-b.y); }
__device__ __forceinline__ float2 cmul(float2 a, float2 b){
  return make_float2(fmaf(a.x, b.x, -(a.y*b.y)), fmaf(a.x, b.y, a.y*b.x));
}

// ---------------- transpose 1: x [B][N][C] fp32 -> xt [B][C][N] bf16 ----------------
__global__ __launch_bounds__(256) void transpose_in_k(const float* __restrict__ in,
                                                      unsigned* __restrict__ out){
  __shared__ float tile[64][33];
  int b  = blockIdx.z;
  int c0 = blockIdx.x * 32;
  int n0 = blockIdx.y * 64;
  int t  = threadIdx.x;
  int tx = t & 31, ty = t >> 5;
  const float* src = in + ((size_t)b * NLEN + n0) * CC + c0;
  #pragma unroll
  for (int k = 0; k < 8; ++k)
    tile[ty + 8*k][tx] = src[(size_t)(ty + 8*k) * CC + tx];
  __syncthreads();
  int lt = t & 15;
  int nl = 4 * lt;
  #pragma unroll
  for (int kk = 0; kk < 2; ++kk){
    int cl = (t >> 4) + 16*kk;
    uint2 u;
    u.x = pack2(tile[nl    ][cl], tile[nl + 1][cl]);
    u.y = pack2(tile[nl + 2][cl], tile[nl + 3][cl]);
    *(uint2*)(out + ((size_t)(b * CC + c0 + cl) * NLEN + n0) / 2 + 2*lt) = u;
  }
}

// ---------------- transpose 2: yt [B][C][N] bf16 -> out [B][N][C] fp32 ----------------
__global__ __launch_bounds__(256) void transpose_out_k(const unsigned* __restrict__ in,
                                                       float* __restrict__ out){
  __shared__ float tile[64][33];
  int b  = blockIdx.z;
  int c0 = blockIdx.x * 32;
  int n0 = blockIdx.y * 64;
  int t  = threadIdx.x;
  int lt = t & 15;
  int nl = 4 * lt;
  #pragma unroll
  for (int kk = 0; kk < 2; ++kk){
    int cl = (t >> 4) + 16*kk;
    uint2 u = *(const uint2*)(in + ((size_t)(b * CC + c0 + cl) * NLEN + n0) / 2 + 2*lt);
    tile[nl    ][cl] = bflo(u.x);
    tile[nl + 1][cl] = bfhi(u.x);
    tile[nl + 2][cl] = bflo(u.y);
    tile[nl + 3][cl] = bfhi(u.y);
  }
  __syncthreads();
  int tx = t & 31, ty = t >> 5;
  float* dst = out + ((size_t)b * NLEN + n0) * CC + c0;
  #pragma unroll
  for (int k = 0; k < 8; ++k)
    dst[(size_t)(ty + 8*k) * CC + tx] = tile[ty + 8*k][tx];
}

// ---------------- Stockham radix-4 pass (512 threads, swizzled LDS) ----------------
template<int SIGN>
__device__ __forceinline__ void fft_pass(const float2* __restrict__ a,
                                         float2* __restrict__ b,
                                         int Ns, int t){
  #pragma unroll
  for (int q = 0; q < 2; ++q){
    int j = t + 512*q;
    float2 v0 = a[IDX(j)];
    float2 v1 = a[IDX(j + 1024)];
    float2 v2 = a[IDX(j + 2048)];
    float2 v3 = a[IDX(j + 3072)];
    int jm = j & (Ns - 1);
    float ang = (float)SIGN * 6.2831853071795864769f * (float)jm / (float)(4*Ns);
    float sn, cs; __sincosf(ang, &sn, &cs);
    float2 w1 = make_float2(cs, sn);
    float2 w2 = cmul(w1, w1);
    float2 w3 = cmul(w2, w1);
    v1 = cmul(v1, w1);
    v2 = cmul(v2, w2);
    v3 = cmul(v3, w3);
    float2 s02 = cadd(v0, v2), d02 = csub(v0, v2);
    float2 s13 = cadd(v1, v3), d13 = csub(v1, v3);
    float2 X0 = cadd(s02, s13);
    float2 X2 = csub(s02, s13);
    float2 id = make_float2(-(float)SIGN * d13.y, (float)SIGN * d13.x);
    float2 X1 = cadd(d02, id);
    float2 X3 = csub(d02, id);
    int idxD = ((j - jm) << 2) + jm;
    b[IDX(idxD       )] = X0;
    b[IDX(idxD +   Ns)] = X1;
    b[IDX(idxD + 2*Ns)] = X2;
    b[IDX(idxD + 3*Ns)] = X3;
  }
}

#define ORTHO_S 0.011048543456039806f   // 1/sqrt(8192)

// ---------------- forward rfft-8192: xt bf16 row -> spec bf16 bins ----------------
__global__ __launch_bounds__(512) void fft_fwd_k(const unsigned* __restrict__ xt,
                                                 unsigned* __restrict__ spec){
  __shared__ float2 bufA[MH];
  __shared__ float2 bufB[MH];
  int t = threadIdx.x;
  size_t row = blockIdx.x;
  const unsigned* src = xt + row * (NLEN/2);
  #pragma unroll
  for (int q = 0; q < 8; ++q){
    int m = t + 512*q;
    unsigned u = src[m];
    bufA[IDX(m)] = make_float2(bflo(u), bfhi(u));   // z[m] = x[2m] + i x[2m+1]
  }
  __syncthreads();
  float2 *pa = bufA, *pb = bufB;
  #pragma unroll
  for (int p = 0; p < 6; ++p){
    int Ns = 1 << (2*p);
    fft_pass<-1>(pa, pb, Ns, t);
    __syncthreads();
    float2* tmp = pa; pa = pb; pb = tmp;
  }
  unsigned* dst = spec + row * (size_t)FP;
  #pragma unroll
  for (int q = 0; q < 8; ++q){
    int k = t + 512*q;
    float2 zk = pa[IDX(k)];
    float2 zc = pa[IDX((MH - k) & (MH - 1))];
    float ex = 0.5f*(zk.x + zc.x);
    float ey = 0.5f*(zk.y - zc.y);
    float ux = zk.x - zc.x;
    float uy = zk.y + zc.y;
    float ox =  0.5f*uy;
    float oy = -0.5f*ux;
    float ang = -6.2831853071795864769f * (float)k / (float)NLEN;
    float sn, cs; __sincosf(ang, &sn, &cs);
    float xr = ex + cs*ox - sn*oy;
    float xi = ey + cs*oy + sn*ox;
    dst[k] = pack2(ORTHO_S*xr, ORTHO_S*xi);
  }
  if (t == 0){
    float2 z0 = pa[IDX(0)];
    dst[MH] = pack2(ORTHO_S*(z0.x - z0.y), 0.0f);   // Nyquist (real)
  }
}

// ---------------- inverse rfft-8192: spec bf16 bins -> yt bf16 row ----------------
__global__ __launch_bounds__(512) void fft_inv_k(const unsigned* __restrict__ spec,
                                                 unsigned* __restrict__ yt){
  __shared__ float2 bufA[MH];
  __shared__ float2 bufB[MH];
  int t = threadIdx.x;
  size_t row = blockIdx.x;
  const unsigned* src = spec + row * (size_t)FP;
  #pragma unroll
  for (int q = 0; q < 8; ++q){
    int k = t + 512*q;
    unsigned uk = src[k];
    unsigned uc = src[MH - k];
    float2 xk = make_float2(bflo(uk), bfhi(uk));
    float2 xc = make_float2(bflo(uc), bfhi(uc));
    if (k == 0){ xk.y = 0.0f; xc.y = 0.0f; }        // drop imag at DC/Nyquist
    float ex = xk.x + xc.x;
    float ey = xk.y - xc.y;
    float dx = xk.x - xc.x;
    float dy = xk.y + xc.y;
    float ang = 6.2831853071795864769f * (float)k / (float)NLEN;
    float sn, cs; __sincosf(ang, &sn, &cs);
    float ox = cs*dx - sn*dy;
    float oy = cs*dy + sn*dx;
    bufA[IDX(k)] = make_float2(ex - oy, ey + ox);
  }
  __syncthreads();
  float2 *pa = bufA, *pb = bufB;
  #pragma unroll
  for (int p = 0; p < 6; ++p){
    int Ns = 1 << (2*p);
    fft_pass<1>(pa, pb, Ns, t);
    __syncthreads();
    float2* tmp = pa; pa = pb; pb = tmp;
  }
  unsigned* dst = yt + row * (NLEN/2);
  #pragma unroll
  for (int q = 0; q < 8; ++q){
    int m = t + 512*q;
    float2 w = pa[IDX(m)];
    dst[m] = pack2(ORTHO_S*w.x, ORTHO_S*w.y);       // y[2m], y[2m+1]
  }
}

// ---------------- weight prep: transpose + bf16 + swizzle (+pi for W2) ----------------
// planes 0,1 (W1 r,i): slot s -> i = s (identity)
// planes 2,3 (W2 r,i): slot s=(ks*4+g)*8+j -> i = (2*ks + (j>>2))*16 + 4*g + (j&3)
// (pi matches the register-built stage-2 A-fragment: lane-group g holds o1 = mt*16+4g+r)
__global__ __launch_bounds__(256) void wprep_k(const float* __restrict__ w1,
                                               const float* __restrict__ w2){
  int t = threadIdx.x;
  int h = blockIdx.x;
  #pragma unroll 4
  for (int u = 0; u < 64; ++u){
    int idx = t + 256*u;          // p*4096 + o*64 + jj
    int p = idx >> 12;
    int o = (idx >> 6) & 63;
    int jj = idx & 63;
    int swo = (o ^ (o >> 3)) & 7;
    int s = (((jj >> 3) ^ swo) << 3) | (jj & 7);   // linear k-slot
    int i;
    if (p < 2){
      i = s;
    } else {
      int ks = s >> 5, g = (s >> 3) & 3, j = s & 7;
      i = (2*ks + (j >> 2))*16 + 4*g + (j & 3);
    }
    const float* src = (p < 2) ? w1 : w2;
    float v = src[(size_t)(p & 1) * 32768 + (size_t)h * 4096 + i * 64 + o];
    g_wprep[(size_t)h * 16384 + idx] = f2bf(v);
  }
}

// ---------------- middle: MFMA bf16 two-stage complex MLP, register handoff ----------------
// block: 64-freq tile x head x batch; 4 waves, wave owns 16 freqs. LDS 48KB -> 3 blocks/CU.
// stage 1: O1^T = W1^T X^T (m=o, n=f, k=i). stage 2: O2 = O1 W2 (m=f, n=o2, k=o1)
// with A-fragments built in registers from stage-1 accumulators (no LDS round-trip).
__global__ __launch_bounds__(256) void afno_mid_mfma_k(const unsigned* __restrict__ spec_in,
                                                       unsigned* __restrict__ spec_out,
                                                       const float* __restrict__ b1,
                                                       const float* __restrict__ b2){
  __shared__ unsigned short lds[24576];   // XR[64][64] XI[64][64] W1R W1I W2R W2I [64][64]
  const int t  = threadIdx.x;
  const int bx = blockIdx.x, h = blockIdx.y, b = blockIdx.z;
  const int F0 = bx * 64;
  const size_t rowbase = ((size_t)b * HH + h) * DH;
  const int l = t & 63, wv = t >> 6;
  const int lf = l & 15, lg = l >> 4;

  // ---- stage W: linear 32KB copy of pre-swizzled bf16 weights ----
  {
    const uint4* gw  = (const uint4*)(g_wprep + (size_t)h * 16384);
    uint4*       sw4 = (uint4*)(lds + 8192);
    #pragma unroll
    for (int u = 0; u < 8; ++u) sw4[t + 256*u] = gw[t + 256*u];
  }
  // ---- stage X: global bf16 bins [i][f] -> LDS planes [f][i], batched loads ----
  {
    unsigned u0[8], u1[8];
    #pragma unroll
    for (int it = 0; it < 8; ++it){
      int ci = wv + 4*it;                  // 0..31
      int fc = ci & 3, pc = ci >> 2;
      int f  = fc*16 + lf;
      int i0 = pc*8 + lg*2;
      int fglob = F0 + f;
      u0[it] = 0; u1[it] = 0;
      if (fglob < FREQ){
        u0[it] = spec_in[(rowbase + i0    ) * (size_t)FP + fglob];
        u1[it] = spec_in[(rowbase + i0 + 1) * (size_t)FP + fglob];
      }
    }
    #pragma unroll
    for (int it = 0; it < 8; ++it){
      int ci = wv + 4*it;
      int fc = ci & 3, pc = ci >> 2;
      int f  = fc*16 + lf;
      int i0 = pc*8 + lg*2;
      unsigned wr = __builtin_amdgcn_perm(u1[it], u0[it], 0x05040100u);
      unsigned wi = __builtin_amdgcn_perm(u1[it], u0[it], 0x07060302u);
      int swf = (f ^ (f >> 3)) & 7;
      int j0  = ((((i0 >> 3) ^ swf) << 3) | (i0 & 7));
      *(unsigned*)(lds        + f*64 + j0) = wr;
      *(unsigned*)(lds + 4096 + f*64 + j0) = wi;
    }
  }
  __syncthreads();

  const int wf0 = wv * 16;
  const unsigned short* XR  = lds;
  const unsigned short* XI  = lds + 4096;
  const unsigned short* W1R = lds + 8192;
  const unsigned short* W1I = lds + 12288;
  const unsigned short* W2R = lds + 16384;
  const unsigned short* W2I = lds + 20480;

  const f32x4 zz = {0.f, 0.f, 0.f, 0.f};
  f32x4 a1R[4], a1I[4];
  #pragma unroll
  for (int mt = 0; mt < 4; ++mt){ a1R[mt] = zz; a1I[mt] = zz; }

  // -------- stage 1: O1^T = W1^T X^T --------
  #pragma unroll
  for (int ks = 0; ks < 2; ++ks){
    int b0 = ks*4 + lg;
    int f  = wf0 + lf;
    int swf = (f ^ (f >> 3)) & 7;
    int offx = f*64 + ((b0 ^ swf) << 3);
    bf16x8 bxr = *(const bf16x8*)(XR + offx);
    bf16x8 bxi = *(const bf16x8*)(XI + offx);
    #pragma unroll
    for (int mt = 0; mt < 4; ++mt){
      int o = mt*16 + lf;
      int swo = (o ^ (o >> 3)) & 7;
      int off = o*64 + ((b0 ^ swo) << 3);
      bf16x8 awr  = *(const bf16x8*)(W1R + off);
      bf16x8 awi  = *(const bf16x8*)(W1I + off);
      bf16x8 awin = awi ^ (short)0x8000;
      a1R[mt] = MFMA(awr,  bxr, a1R[mt]);
      a1R[mt] = MFMA(awin, bxi, a1R[mt]);
      a1I[mt] = MFMA(awi,  bxr, a1I[mt]);
      a1I[mt] = MFMA(awr,  bxi, a1I[mt]);
    }
  }

  // -------- stage-1 epilogue in registers: bias + GELU -> stage-2 A-fragments --------
  // k-slot (ks, g=lg, j): o1 = (2ks + (j>>2))*16 + 4g + (j&3)  (matches wprep pi)
  bf16x8 aFr[2], aFi[2], aFin[2];
  #pragma unroll
  for (int ks = 0; ks < 2; ++ks){
    unsigned wr_[4], wi_[4];
    #pragma unroll
    for (int half = 0; half < 2; ++half){          // j>>2
      int mt = 2*ks + half;
      float4 br = *(const float4*)(b1 +       (size_t)h*64 + mt*16 + lg*4);
      float4 bi = *(const float4*)(b1 + 512 + (size_t)h*64 + mt*16 + lg*4);
      float vr0 = gelu_fast(a1R[mt][0] + br.x), vr1 = gelu_fast(a1R[mt][1] + br.y);
      float vr2 = gelu_fast(a1R[mt][2] + br.z), vr3 = gelu_fast(a1R[mt][3] + br.w);
      float vi0 = gelu_fast(a1I[mt][0] + bi.x), vi1 = gelu_fast(a1I[mt][1] + bi.y);
      float vi2 = gelu_fast(a1I[mt][2] + bi.z), vi3 = gelu_fast(a1I[mt][3] + bi.w);
      wr_[half*2    ] = pack2(vr0, vr1);
      wr_[half*2 + 1] = pack2(vr2, vr3);
      wi_[half*2    ] = pack2(vi0, vi1);
      wi_[half*2 + 1] = pack2(vi2, vi3);
    }
    unsigned* pr = (unsigned*)&aFr[ks];
    unsigned* pi = (unsigned*)&aFi[ks];
    #pragma unroll
    for (int w = 0; w < 4; ++w){ pr[w] = wr_[w]; pi[w] = wi_[w]; }
    aFin[ks] = aFi[ks] ^ (short)0x8000;
  }

  // -------- stage 2: O2 = O1 W2 (A from registers, B = W2 from LDS) --------
  f32x4 a2R[4], a2I[4];
  #pragma unroll
  for (int nt = 0; nt < 4; ++nt){ a2R[nt] = zz; a2I[nt] = zz; }

  #pragma unroll
  for (int ks = 0; ks < 2; ++ks){
    int b0 = ks*4 + lg;
    #pragma unroll
    for (int nt = 0; nt < 4; ++nt){
      int o2 = nt*16 + lf;
      int swo = (o2 ^ (o2 >> 3)) & 7;
      int off = o2*64 + ((b0 ^ swo) << 3);
      bf16x8 bwr = *(const bf16x8*)(W2R + off);
      bf16x8 bwi = *(const bf16x8*)(W2I + off);
      a2R[nt] = MFMA(aFr[ks],  bwr, a2R[nt]);
      a2R[nt] = MFMA(aFin[ks], bwi, a2R[nt]);
      a2I[nt] = MFMA(aFi[ks],  bwr, a2I[nt]);
      a2I[nt] = MFMA(aFr[ks],  bwi, a2I[nt]);
    }
  }

  // -------- stage-2 epilogue: bias + wide 16B stores --------
  // C-layout: col = o2 = lf (+nt*16), row = f = 4*lg + r (+wf0 + F0)
  int f0 = F0 + wf0 + lg*4;
  if (f0 <= MH){                                   // bins f0..f0+3 stay inside FP padding
    #pragma unroll
    for (int nt = 0; nt < 4; ++nt){
      int o2 = nt*16 + lf;
      float b2r = b2[(size_t)h*64 + o2];
      float b2i = b2[512 + (size_t)h*64 + o2];
      uint4 st;
      st.x = pack2(a2R[nt][0] + b2r, a2I[nt][0] + b2i);
      st.y = pack2(a2R[nt][1] + b2r, a2I[nt][1] + b2i);
      st.z = pack2(a2R[nt][2] + b2r, a2I[nt][2] + b2i);
      st.w = pack2(a2R[nt][3] + b2r, a2I[nt][3] + b2i);
      *(uint4*)(spec_out + (rowbase + o2) * (size_t)FP + f0) = st;
    }
  }
}

// ---------------- launch ----------------
extern "C" void kernel_launch(void* const* d_in, const int* in_sizes, int n_in,
                              void* d_out, int out_size, void* d_ws, size_t ws_size,
                              hipStream_t stream) {
  const float* x  = (const float*)d_in[0];
  const float* w1 = (const float*)d_in[1];
  const float* b1 = (const float*)d_in[2];
  const float* w2 = (const float*)d_in[3];
  const float* b2 = (const float*)d_in[4];
  float* out = (float*)d_out;

  unsigned char* base = (unsigned char*)d_ws;
  if (ws_size < 2 * REGION_BYTES){
    void* p = nullptr;
    hipGetSymbolAddress(&p, HIP_SYMBOL(g_scratch));
    base = (unsigned char*)p;
  }
  unsigned* specA = (unsigned*)base;                 // region A: spectrum1, later yt
  unsigned char* regB = base + REGION_BYTES;         // region B: xt, later spectrum2
  unsigned* xt    = (unsigned*)regB;
  unsigned* specB = (unsigned*)regB;
  unsigned* ytp   = (unsigned*)base;

  // 0) weight prep (bf16 + transpose + swizzle + stage-2 pi)
  wprep_k<<<8, 256, 0, stream>>>(w1, w2);
  // 1) transpose x [B][N][C] fp32 -> xt [B][C][N] bf16
  transpose_in_k<<<dim3(CC/32, NLEN/64, BB), 256, 0, stream>>>(x, xt);
  // 2) forward rfft per row
  fft_fwd_k<<<NSEQ, 512, 0, stream>>>(xt, specA);
  // 3) per-frequency two-stage complex MLP (bf16 MFMA, register handoff)
  afno_mid_mfma_k<<<dim3(65, HH, BB), 256, 0, stream>>>(specA, specB, b1, b2);
  // 4) inverse rfft per row
  fft_inv_k<<<NSEQ, 512, 0, stream>>>(specB, ytp);
  // 5) transpose yt [B][C][N] bf16 -> out [B][N][C] fp32
  transpose_out_k<<<dim3(CC/32, NLEN/64, BB), 256, 0, stream>>>(ytp, out);
}

// Round 6
// 213.731 us; speedup vs baseline: 2.3289x; 1.0965x over previous
//
#include <hip/hip_runtime.h>
#include <math.h>

// ---------------- problem constants ----------------
#define BB    8
#define NLEN  8192          // sequence length (FFT size)
#define CC    512           // channels
#define HH    8             // heads
#define DH    64            // head dim
#define MH    4096          // NLEN/2 (complex FFT size)
#define FREQ  4097          // rfft bins
#define FP    4104          // padded spectrum row length (uint bins)
#define NSEQ  (BB*CC)       // 4096 rows

// scratch: two regions of NSEQ*FP uint (bf16 (r,i) packed bins)
#define REGION_BYTES ((size_t)NSEQ * FP * 4ull)

static __device__ __align__(256) unsigned char g_scratch[2ull * (size_t)NSEQ * FP * 4ull];
// prepped weights: [h][plane(0=w1r,1=w1i,2=w2r,3=w2i)][o][swizzled k-slot] bf16
__device__ unsigned short g_wprep[8 * 4 * 64 * 64];

typedef __attribute__((ext_vector_type(8))) short bf16x8;
typedef __attribute__((ext_vector_type(4))) float f32x4;

__device__ __forceinline__ f32x4 MFMA(bf16x8 a, bf16x8 b, f32x4 c){
  return __builtin_amdgcn_mfma_f32_16x16x32_bf16(a, b, c, 0, 0, 0);
}

__device__ __forceinline__ unsigned short f2bf(float f){
  unsigned u = __float_as_uint(f);
  return (unsigned short)((u + 0x7fffu + ((u >> 16) & 1u)) >> 16);
}
__device__ __forceinline__ unsigned pack2(float a, float b){
  return (unsigned)f2bf(a) | ((unsigned)f2bf(b) << 16);
}
__device__ __forceinline__ float bflo(unsigned u){ return __uint_as_float(u << 16); }
__device__ __forceinline__ float bfhi(unsigned u){ return __uint_as_float(u & 0xffff0000u); }

// fast exact-enough GELU: Abramowitz-Stegun 7.1.26 erf (max err 1.5e-7)
__device__ __forceinline__ float gelu_fast(float v){
  float x  = v * 0.70710678118654752440f;
  float ax = fabsf(x);
  float t  = __builtin_amdgcn_rcpf(fmaf(0.3275911f, ax, 1.0f));
  float p  = fmaf(fmaf(fmaf(fmaf(1.061405429f, t, -1.453152027f), t,
                            1.421413741f), t, -0.284496736f), t, 0.254829592f);
  float e  = __expf(-x * x);
  float erf_ax = fmaf(-p * t, e, 1.0f);
  float erfx = copysignf(erf_ax, x);
  return 0.5f * v * (1.0f + erfx);
}

// ---------------- complex helpers ----------------
__device__ __forceinline__ float2 cadd(float2 a, float2 b){ return make_float2(a.x+b.x, a.y+b.y); }
__device__ __forceinline__ float2 csub(float2 a, float2 b){ return make_float2(a.x-b.x, a.y-b.y); }
__device__ __forceinline__ float2 cmul(float2 a, float2 b){
  return make_float2(fmaf(a.x, b.x, -(a.y*b.y)), fmaf(a.x, b.y, a.y*b.x));
}

// ---------------- transpose 1: x [B][N][C] fp32 -> xt [B][C][N] bf16 ----------------
__global__ __launch_bounds__(256) void transpose_in_k(const float* __restrict__ in,
                                                      unsigned* __restrict__ out){
  __shared__ float tile[64][33];
  int b  = blockIdx.z;
  int c0 = blockIdx.x * 32;
  int n0 = blockIdx.y * 64;
  int t  = threadIdx.x;
  int tx = t & 31, ty = t >> 5;
  const float* src = in + ((size_t)b * NLEN + n0) * CC + c0;
  #pragma unroll
  for (int k = 0; k < 8; ++k)
    tile[ty + 8*k][tx] = src[(size_t)(ty + 8*k) * CC + tx];
  __syncthreads();
  int lt = t & 15;
  int nl = 4 * lt;
  #pragma unroll
  for (int kk = 0; kk < 2; ++kk){
    int cl = (t >> 4) + 16*kk;
    uint2 u;
    u.x = pack2(tile[nl    ][cl], tile[nl + 1][cl]);
    u.y = pack2(tile[nl + 2][cl], tile[nl + 3][cl]);
    *(uint2*)(out + ((size_t)(b * CC + c0 + cl) * NLEN + n0) / 2 + 2*lt) = u;
  }
}

// ---------------- transpose 2: yt [B][C][N] bf16 -> out [B][N][C] fp32 ----------------
__global__ __launch_bounds__(256) void transpose_out_k(const unsigned* __restrict__ in,
                                                       float* __restrict__ out){
  __shared__ float tile[64][33];
  int b  = blockIdx.z;
  int c0 = blockIdx.x * 32;
  int n0 = blockIdx.y * 64;
  int t  = threadIdx.x;
  int lt = t & 15;
  int nl = 4 * lt;
  #pragma unroll
  for (int kk = 0; kk < 2; ++kk){
    int cl = (t >> 4) + 16*kk;
    uint2 u = *(const uint2*)(in + ((size_t)(b * CC + c0 + cl) * NLEN + n0) / 2 + 2*lt);
    tile[nl    ][cl] = bflo(u.x);
    tile[nl + 1][cl] = bfhi(u.x);
    tile[nl + 2][cl] = bflo(u.y);
    tile[nl + 3][cl] = bfhi(u.y);
  }
  __syncthreads();
  int tx = t & 31, ty = t >> 5;
  float* dst = out + ((size_t)b * NLEN + n0) * CC + c0;
  #pragma unroll
  for (int k = 0; k < 8; ++k)
    dst[(size_t)(ty + 8*k) * CC + tx] = tile[ty + 8*k][tx];
}

// ================= radix-16 register FFT (N=4096, 256 threads, 3 passes) =================
// LDS slot padding: +1 float2 per 16 -> conflict-free exchanges
#define SL(e) ((e) + ((e) >> 4))
#define PERM16(p) ((((p) & 3) << 2) | ((p) >> 2))   // X[p] lives in v[PERM16(p)] after dft16ip

template<int SIGN>
__device__ __forceinline__ void dft4ip(float2& v0, float2& v1, float2& v2, float2& v3){
  float2 s02 = cadd(v0, v2), d02 = csub(v0, v2);
  float2 s13 = cadd(v1, v3), d13 = csub(v1, v3);
  float2 id = make_float2(-(float)SIGN * d13.y, (float)SIGN * d13.x);
  v0 = cadd(s02, s13);
  v1 = cadd(d02, id);
  v2 = csub(s02, s13);
  v3 = csub(d02, id);
}

template<int SIGN>
__device__ __forceinline__ float2 w16c(int m){   // e^{SIGN*2pi*i*m/16}, m in {1,2,3,4,6,9}
  const float c1 = 0.9238795325112867f, s1 = 0.3826834323650898f, r = 0.7071067811865476f;
  float cs = 1.f, sn = 0.f;
  if (m == 1){ cs = c1;  sn = s1; }
  else if (m == 2){ cs = r;   sn = r; }
  else if (m == 3){ cs = s1;  sn = c1; }
  else if (m == 4){ cs = 0.f; sn = 1.f; }
  else if (m == 6){ cs = -r;  sn = r; }
  else if (m == 9){ cs = -c1; sn = -s1; }
  return make_float2(cs, (float)SIGN * sn);
}

template<int SIGN>
__device__ __forceinline__ void dft16ip(float2 v[16]){
  // stage A: DFT4 over q1 (stride 4); A[q0][p0] -> v[q0+4*p0]
  #pragma unroll
  for (int q0 = 0; q0 < 4; ++q0) dft4ip<SIGN>(v[q0], v[q0+4], v[q0+8], v[q0+12]);
  // twiddle by w16^{p0*q0}
  #pragma unroll
  for (int p0 = 0; p0 < 4; ++p0)
    #pragma unroll
    for (int q0 = 0; q0 < 4; ++q0){
      const int m = p0 * q0;
      if (m) v[q0 + 4*p0] = cmul(v[q0 + 4*p0], w16c<SIGN>(m));
    }
  // stage B: DFT4 over q0 (stride 1); X[p0+4*p1] -> v[4*p0+p1]
  #pragma unroll
  for (int p0 = 0; p0 < 4; ++p0) dft4ip<SIGN>(v[4*p0], v[4*p0+1], v[4*p0+2], v[4*p0+3]);
}

template<int SIGN>
__device__ __forceinline__ void twiddle16(float2 v[16], int jm, float invRNs){
  float ang = (float)SIGN * 6.2831853071795864769f * (float)jm * invRNs;
  float sn, cs; __sincosf(ang, &sn, &cs);
  float2 w1 = make_float2(cs, sn), w = w1;
  #pragma unroll
  for (int q = 1; q < 16; ++q){ v[q] = cmul(v[q], w); w = cmul(w, w1); }
}

// passes 2 & 3 (LDS exchange in, compute, LDS write); caller barriers around writes
template<int SIGN, int NS>
__device__ __forceinline__ void fft_mid_pass(float2* lds2, float2 v[16], int t){
  #pragma unroll
  for (int q = 0; q < 16; ++q) v[q] = lds2[SL(t + 256*q)];
  int jm = t & (NS - 1);
  twiddle16<SIGN>(v, jm, 1.0f / (16.0f * (float)NS));
  dft16ip<SIGN>(v);
  __syncthreads();                        // all reads done before overwrite
  int base = ((t - jm) << 4) + jm;
  #pragma unroll
  for (int p = 0; p < 16; ++p) lds2[SL(base + p*NS)] = v[PERM16(p)];
  __syncthreads();
}

#define ORTHO_S 0.011048543456039806f   // 1/sqrt(8192)

// ---------------- forward rfft-8192: xt bf16 row -> spec bf16 bins ----------------
__global__ __launch_bounds__(256) void fft_fwd_k(const unsigned* __restrict__ xt,
                                                 unsigned* __restrict__ spec){
  __shared__ float2 lds2[4352];
  int t = threadIdx.x;
  size_t row = blockIdx.x;
  const unsigned* src = xt + row * (NLEN/2);
  float2 v[16];
  // pass 1 (Ns=1, jm=0): load straight into registers
  #pragma unroll
  for (int q = 0; q < 16; ++q){
    unsigned u = src[t + 256*q];
    v[q] = make_float2(bflo(u), bfhi(u));   // z[m] = x[2m] + i x[2m+1]
  }
  dft16ip<-1>(v);
  #pragma unroll
  for (int p = 0; p < 16; ++p) lds2[SL(16*t + p)] = v[PERM16(p)];
  __syncthreads();
  fft_mid_pass<-1, 16 >(lds2, v, t);        // pass 2
  fft_mid_pass<-1, 256>(lds2, v, t);        // pass 3 -> natural-order FFT in LDS
  // unpack packed-complex FFT into rfft bins, ortho scale
  unsigned* dst = spec + row * (size_t)FP;
  #pragma unroll
  for (int q = 0; q < 16; ++q){
    int k = t + 256*q;
    float2 zk = lds2[SL(k)];
    float2 zc = lds2[SL((MH - k) & (MH - 1))];
    float ex = 0.5f*(zk.x + zc.x);
    float ey = 0.5f*(zk.y - zc.y);
    float ux = zk.x - zc.x;
    float uy = zk.y + zc.y;
    float ox =  0.5f*uy;
    float oy = -0.5f*ux;
    float ang = -6.2831853071795864769f * (float)k / (float)NLEN;
    float sn, cs; __sincosf(ang, &sn, &cs);
    float xr = ex + cs*ox - sn*oy;
    float xi = ey + cs*oy + sn*ox;
    dst[k] = pack2(ORTHO_S*xr, ORTHO_S*xi);
  }
  if (t == 0){
    float2 z0 = lds2[SL(0)];
    dst[MH] = pack2(ORTHO_S*(z0.x - z0.y), 0.0f);   // Nyquist (real)
  }
}

// ---------------- inverse rfft-8192: spec bf16 bins -> yt bf16 row ----------------
__global__ __launch_bounds__(256) void fft_inv_k(const unsigned* __restrict__ spec,
                                                 unsigned* __restrict__ yt){
  __shared__ float2 lds2[4352];
  int t = threadIdx.x;
  size_t row = blockIdx.x;
  const unsigned* src = spec + row * (size_t)FP;
  float2 v[16];
  // prep + pass 1 (Ns=1): build Z[k] for k = t+256q straight into registers
  #pragma unroll
  for (int q = 0; q < 16; ++q){
    int k = t + 256*q;
    unsigned uk = src[k];
    unsigned uc = src[MH - k];
    float2 xk = make_float2(bflo(uk), bfhi(uk));
    float2 xc = make_float2(bflo(uc), bfhi(uc));
    if (k == 0){ xk.y = 0.0f; xc.y = 0.0f; }        // drop imag at DC/Nyquist
    float ex = xk.x + xc.x;
    float ey = xk.y - xc.y;
    float dx = xk.x - xc.x;
    float dy = xk.y + xc.y;
    float ang = 6.2831853071795864769f * (float)k / (float)NLEN;
    float sn, cs; __sincosf(ang, &sn, &cs);
    float ox = cs*dx - sn*dy;
    float oy = cs*dy + sn*dx;
    v[q] = make_float2(ex - oy, ey + ox);           // Z = E' + i O'
  }
  dft16ip<1>(v);
  #pragma unroll
  for (int p = 0; p < 16; ++p) lds2[SL(16*t + p)] = v[PERM16(p)];
  __syncthreads();
  fft_mid_pass<1, 16 >(lds2, v, t);
  fft_mid_pass<1, 256>(lds2, v, t);
  unsigned* dst = yt + row * (NLEN/2);
  #pragma unroll
  for (int q = 0; q < 16; ++q){
    int m = t + 256*q;
    float2 w = lds2[SL(m)];
    dst[m] = pack2(ORTHO_S*w.x, ORTHO_S*w.y);       // y[2m], y[2m+1]
  }
}

// ---------------- weight prep: transpose + bf16 + swizzle (+pi for W2) ----------------
// planes 0,1 (W1 r,i): slot s -> i = s (identity)
// planes 2,3 (W2 r,i): slot s=(ks*4+g)*8+j -> i = (2*ks + (j>>2))*16 + 4*g + (j&3)
__global__ __launch_bounds__(256) void wprep_k(const float* __restrict__ w1,
                                               const float* __restrict__ w2){
  int t = threadIdx.x;
  int h = blockIdx.x;
  #pragma unroll 4
  for (int u = 0; u < 64; ++u){
    int idx = t + 256*u;          // p*4096 + o*64 + jj
    int p = idx >> 12;
    int o = (idx >> 6) & 63;
    int jj = idx & 63;
    int swo = (o ^ (o >> 3)) & 7;
    int s = (((jj >> 3) ^ swo) << 3) | (jj & 7);   // linear k-slot
    int i;
    if (p < 2){
      i = s;
    } else {
      int ks = s >> 5, g = (s >> 3) & 3, j = s & 7;
      i = (2*ks + (j >> 2))*16 + 4*g + (j & 3);
    }
    const float* src = (p < 2) ? w1 : w2;
    float v = src[(size_t)(p & 1) * 32768 + (size_t)h * 4096 + i * 64 + o];
    g_wprep[(size_t)h * 16384 + idx] = f2bf(v);
  }
}

// ---------------- middle: MFMA bf16 two-stage complex MLP, register handoff ----------------
__global__ __launch_bounds__(256) void afno_mid_mfma_k(const unsigned* __restrict__ spec_in,
                                                       unsigned* __restrict__ spec_out,
                                                       const float* __restrict__ b1,
                                                       const float* __restrict__ b2){
  __shared__ unsigned short lds[24576];   // XR[64][64] XI[64][64] W1R W1I W2R W2I [64][64]
  const int t  = threadIdx.x;
  const int bx = blockIdx.x, h = blockIdx.y, b = blockIdx.z;
  const int F0 = bx * 64;
  const size_t rowbase = ((size_t)b * HH + h) * DH;
  const int l = t & 63, wv = t >> 6;
  const int lf = l & 15, lg = l >> 4;

  // ---- stage W: linear 32KB copy of pre-swizzled bf16 weights ----
  {
    const uint4* gw  = (const uint4*)(g_wprep + (size_t)h * 16384);
    uint4*       sw4 = (uint4*)(lds + 8192);
    #pragma unroll
    for (int u = 0; u < 8; ++u) sw4[t + 256*u] = gw[t + 256*u];
  }
  // ---- stage X: global bf16 bins [i][f] -> LDS planes [f][i], batched loads ----
  {
    unsigned u0[8], u1[8];
    #pragma unroll
    for (int it = 0; it < 8; ++it){
      int ci = wv + 4*it;                  // 0..31
      int fc = ci & 3, pc = ci >> 2;
      int f  = fc*16 + lf;
      int i0 = pc*8 + lg*2;
      int fglob = F0 + f;
      u0[it] = 0; u1[it] = 0;
      if (fglob < FREQ){
        u0[it] = spec_in[(rowbase + i0    ) * (size_t)FP + fglob];
        u1[it] = spec_in[(rowbase + i0 + 1) * (size_t)FP + fglob];
      }
    }
    #pragma unroll
    for (int it = 0; it < 8; ++it){
      int ci = wv + 4*it;
      int fc = ci & 3, pc = ci >> 2;
      int f  = fc*16 + lf;
      int i0 = pc*8 + lg*2;
      unsigned wr = __builtin_amdgcn_perm(u1[it], u0[it], 0x05040100u);
      unsigned wi = __builtin_amdgcn_perm(u1[it], u0[it], 0x07060302u);
      int swf = (f ^ (f >> 3)) & 7;
      int j0  = ((((i0 >> 3) ^ swf) << 3) | (i0 & 7));
      *(unsigned*)(lds        + f*64 + j0) = wr;
      *(unsigned*)(lds + 4096 + f*64 + j0) = wi;
    }
  }
  __syncthreads();

  const int wf0 = wv * 16;
  const unsigned short* XR  = lds;
  const unsigned short* XI  = lds + 4096;
  const unsigned short* W1R = lds + 8192;
  const unsigned short* W1I = lds + 12288;
  const unsigned short* W2R = lds + 16384;
  const unsigned short* W2I = lds + 20480;

  const f32x4 zz = {0.f, 0.f, 0.f, 0.f};
  f32x4 a1R[4], a1I[4];
  #pragma unroll
  for (int mt = 0; mt < 4; ++mt){ a1R[mt] = zz; a1I[mt] = zz; }

  // -------- stage 1: O1^T = W1^T X^T --------
  #pragma unroll
  for (int ks = 0; ks < 2; ++ks){
    int b0 = ks*4 + lg;
    int f  = wf0 + lf;
    int swf = (f ^ (f >> 3)) & 7;
    int offx = f*64 + ((b0 ^ swf) << 3);
    bf16x8 bxr = *(const bf16x8*)(XR + offx);
    bf16x8 bxi = *(const bf16x8*)(XI + offx);
    #pragma unroll
    for (int mt = 0; mt < 4; ++mt){
      int o = mt*16 + lf;
      int swo = (o ^ (o >> 3)) & 7;
      int off = o*64 + ((b0 ^ swo) << 3);
      bf16x8 awr  = *(const bf16x8*)(W1R + off);
      bf16x8 awi  = *(const bf16x8*)(W1I + off);
      bf16x8 awin = awi ^ (short)0x8000;
      a1R[mt] = MFMA(awr,  bxr, a1R[mt]);
      a1R[mt] = MFMA(awin, bxi, a1R[mt]);
      a1I[mt] = MFMA(awi,  bxr, a1I[mt]);
      a1I[mt] = MFMA(awr,  bxi, a1I[mt]);
    }
  }

  // -------- stage-1 epilogue in registers: bias + GELU -> stage-2 A-fragments --------
  bf16x8 aFr[2], aFi[2], aFin[2];
  #pragma unroll
  for (int ks = 0; ks < 2; ++ks){
    unsigned wr_[4], wi_[4];
    #pragma unroll
    for (int half = 0; half < 2; ++half){          // j>>2
      int mt = 2*ks + half;
      float4 br = *(const float4*)(b1 +       (size_t)h*64 + mt*16 + lg*4);
      float4 bi = *(const float4*)(b1 + 512 + (size_t)h*64 + mt*16 + lg*4);
      float vr0 = gelu_fast(a1R[mt][0] + br.x), vr1 = gelu_fast(a1R[mt][1] + br.y);
      float vr2 = gelu_fast(a1R[mt][2] + br.z), vr3 = gelu_fast(a1R[mt][3] + br.w);
      float vi0 = gelu_fast(a1I[mt][0] + bi.x), vi1 = gelu_fast(a1I[mt][1] + bi.y);
      float vi2 = gelu_fast(a1I[mt][2] + bi.z), vi3 = gelu_fast(a1I[mt][3] + bi.w);
      wr_[half*2    ] = pack2(vr0, vr1);
      wr_[half*2 + 1] = pack2(vr2, vr3);
      wi_[half*2    ] = pack2(vi0, vi1);
      wi_[half*2 + 1] = pack2(vi2, vi3);
    }
    unsigned* pr = (unsigned*)&aFr[ks];
    unsigned* pi = (unsigned*)&aFi[ks];
    #pragma unroll
    for (int w = 0; w < 4; ++w){ pr[w] = wr_[w]; pi[w] = wi_[w]; }
    aFin[ks] = aFi[ks] ^ (short)0x8000;
  }

  // -------- stage 2: O2 = O1 W2 (A from registers, B = W2 from LDS) --------
  f32x4 a2R[4], a2I[4];
  #pragma unroll
  for (int nt = 0; nt < 4; ++nt){ a2R[nt] = zz; a2I[nt] = zz; }

  #pragma unroll
  for (int ks = 0; ks < 2; ++ks){
    int b0 = ks*4 + lg;
    #pragma unroll
    for (int nt = 0; nt < 4; ++nt){
      int o2 = nt*16 + lf;
      int swo = (o2 ^ (o2 >> 3)) & 7;
      int off = o2*64 + ((b0 ^ swo) << 3);
      bf16x8 bwr = *(const bf16x8*)(W2R + off);
      bf16x8 bwi = *(const bf16x8*)(W2I + off);
      a2R[nt] = MFMA(aFr[ks],  bwr, a2R[nt]);
      a2R[nt] = MFMA(aFin[ks], bwi, a2R[nt]);
      a2I[nt] = MFMA(aFi[ks],  bwr, a2I[nt]);
      a2I[nt] = MFMA(aFr[ks],  bwi, a2I[nt]);
    }
  }

  // -------- stage-2 epilogue: bias + wide 16B stores --------
  int f0 = F0 + wf0 + lg*4;
  if (f0 <= MH){
    #pragma unroll
    for (int nt = 0; nt < 4; ++nt){
      int o2 = nt*16 + lf;
      float b2r = b2[(size_t)h*64 + o2];
      float b2i = b2[512 + (size_t)h*64 + o2];
      uint4 st;
      st.x = pack2(a2R[nt][0] + b2r, a2I[nt][0] + b2i);
      st.y = pack2(a2R[nt][1] + b2r, a2I[nt][1] + b2i);
      st.z = pack2(a2R[nt][2] + b2r, a2I[nt][2] + b2i);
      st.w = pack2(a2R[nt][3] + b2r, a2I[nt][3] + b2i);
      *(uint4*)(spec_out + (rowbase + o2) * (size_t)FP + f0) = st;
    }
  }
}

// ---------------- launch ----------------
extern "C" void kernel_launch(void* const* d_in, const int* in_sizes, int n_in,
                              void* d_out, int out_size, void* d_ws, size_t ws_size,
                              hipStream_t stream) {
  const float* x  = (const float*)d_in[0];
  const float* w1 = (const float*)d_in[1];
  const float* b1 = (const float*)d_in[2];
  const float* w2 = (const float*)d_in[3];
  const float* b2 = (const float*)d_in[4];
  float* out = (float*)d_out;

  unsigned char* base = (unsigned char*)d_ws;
  if (ws_size < 2 * REGION_BYTES){
    void* p = nullptr;
    hipGetSymbolAddress(&p, HIP_SYMBOL(g_scratch));
    base = (unsigned char*)p;
  }
  unsigned* specA = (unsigned*)base;                 // region A: spectrum1, later yt
  unsigned char* regB = base + REGION_BYTES;         // region B: xt, later spectrum2
  unsigned* xt    = (unsigned*)regB;
  unsigned* specB = (unsigned*)regB;
  unsigned* ytp   = (unsigned*)base;

  // 0) weight prep (bf16 + transpose + swizzle + stage-2 pi)
  wprep_k<<<8, 256, 0, stream>>>(w1, w2);
  // 1) transpose x [B][N][C] fp32 -> xt [B][C][N] bf16
  transpose_in_k<<<dim3(CC/32, NLEN/64, BB), 256, 0, stream>>>(x, xt);
  // 2) forward rfft per row (radix-16 register FFT)
  fft_fwd_k<<<NSEQ, 256, 0, stream>>>(xt, specA);
  // 3) per-frequency two-stage complex MLP (bf16 MFMA, register handoff)
  afno_mid_mfma_k<<<dim3(65, HH, BB), 256, 0, stream>>>(specA, specB, b1, b2);
  // 4) inverse rfft per row (radix-16 register FFT)
  fft_inv_k<<<NSEQ, 256, 0, stream>>>(specB, ytp);
  // 5) transpose yt [B][C][N] bf16 -> out [B][N][C] fp32
  transpose_out_k<<<dim3(CC/32, NLEN/64, BB), 256, 0, stream>>>(ytp, out);
}